// Round 1
// baseline (313.106 us; speedup 1.0000x reference)
//
#include <hip/hip_runtime.h>
#include <cstdint>

typedef unsigned short u16;
typedef __bf16 bf16x8 __attribute__((ext_vector_type(8)));
typedef float f32x4 __attribute__((ext_vector_type(4)));

// ---------- bf16 helpers (RNE) ----------
__device__ __forceinline__ u16 f2bf(float f) {
    unsigned u = __float_as_uint(f);
    u += 0x7fffu + ((u >> 16) & 1u);
    return (u16)(u >> 16);
}
__device__ __forceinline__ float bf2f(u16 h) {
    return __uint_as_float(((unsigned)h) << 16);
}

// ---------- async global->LDS (16B per lane, wave-uniform LDS base) ----------
__device__ __forceinline__ void lds16(const void* g, void* l) {
    __builtin_amdgcn_global_load_lds(
        (const __attribute__((address_space(1))) void*)g,
        (__attribute__((address_space(3))) void*)l, 16, 0, 0);
}

// ================= prep: x = seq + positional; write f32 + bf16 =================
__global__ __launch_bounds__(256) void prep_x(const float* __restrict__ seq,
                                              float* __restrict__ x,
                                              u16* __restrict__ xb) {
    size_t i = (size_t)blockIdx.x * 256 + threadIdx.x;   // float4 index, 2M total
    int e4 = (int)(i & 255) * 4;
    int l  = (int)((i >> 8) & 2047);
    float4 s = ((const float4*)seq)[i];
    float v[4] = {s.x, s.y, s.z, s.w};
    const float c = -13.287712379549449f / 512.0f;       // -log2(10000)/512
#pragma unroll
    for (int j = 0; j < 4; j++) {
        int e  = e4 + j;
        int ii = e & 511;
        float st  = exp2f(c * (float)ii);
        float arg = (float)l * st;
        v[j] += (e < 512) ? sinf(arg) : cosf(arg);
    }
    float4 o; o.x = v[0]; o.y = v[1]; o.z = v[2]; o.w = v[3];
    ((float4*)x)[i] = o;
    ushort4 ob; ob.x = f2bf(v[0]); ob.y = f2bf(v[1]); ob.z = f2bf(v[2]); ob.w = f2bf(v[3]);
    ((ushort4*)xb)[i] = ob;
}

// ===== weights: mats 0..3 = transpose(W)->bf16 (B^T layout), mat 4 = lin_W direct =====
__global__ void prep_w(const float* __restrict__ wq, const float* __restrict__ wk,
                       const float* __restrict__ wv, const float* __restrict__ wo,
                       const float* __restrict__ wl, u16* __restrict__ wt) {
    int mat = blockIdx.z;
    const float* src = (mat == 0) ? wq : (mat == 1) ? wk : (mat == 2) ? wv : (mat == 3) ? wo : wl;
    u16* dst = wt + (size_t)mat * 1024 * 1024;
    int tx = threadIdx.x, ty = threadIdx.y;
    if (mat == 4) {
        int col = blockIdx.x * 32 + tx, row0 = blockIdx.y * 32;
#pragma unroll
        for (int j = 0; j < 32; j += 8)
            dst[(size_t)(row0 + ty + j) * 1024 + col] = f2bf(src[(size_t)(row0 + ty + j) * 1024 + col]);
    } else {
        __shared__ float tile[32][33];
        int col = blockIdx.x * 32 + tx, row0 = blockIdx.y * 32;
#pragma unroll
        for (int j = 0; j < 32; j += 8)
            tile[ty + j][tx] = src[(size_t)(row0 + ty + j) * 1024 + col];
        __syncthreads();
        int col2 = blockIdx.y * 32 + tx, row20 = blockIdx.x * 32;
#pragma unroll
        for (int j = 0; j < 32; j += 8)
            dst[(size_t)(row20 + ty + j) * 1024 + col2] = f2bf(tile[tx][ty + j]);
    }
}

// ================= m97-structure 128x128 bf16 GEMM, B^T input =================
// EPI: 0 = fp32 out, 1 = fp32 bias+relu out, 2 = bf16 out
template <int EPI>
__global__ __launch_bounds__(256) void gemm_bt(const u16* __restrict__ A,   // [M,K] bf16
                                               const u16* __restrict__ Bt,  // [N,K] bf16
                                               void* __restrict__ Cv,
                                               const float* __restrict__ bias,
                                               int M, int N, int K) {
    __shared__ __align__(16) u16 As[128 * 32];
    __shared__ __align__(16) u16 Bs[128 * 32];
    const int t = threadIdx.x;
    const int ntn = N >> 7;
    const int tm = blockIdx.x / ntn, tn = blockIdx.x % ntn;
    const size_t m0 = (size_t)tm << 7, n0 = (size_t)tn << 7;
    const int w = t >> 6, lane = t & 63;
    const int wr = w >> 1, wc = w & 1;

    f32x4 acc[4][4];
#pragma unroll
    for (int i = 0; i < 4; i++)
#pragma unroll
        for (int j = 0; j < 4; j++)
#pragma unroll
            for (int r = 0; r < 4; r++) acc[i][j][r] = 0.0f;

    const int srow = t >> 2, sseg = (t & 3) << 3;            // staging: row, 8-elem segment
    const u16* aG0 = A  + (m0 + srow) * (size_t)K + sseg;
    const u16* aG1 = aG0 + (size_t)64 * K;
    const u16* bG0 = Bt + (n0 + srow) * (size_t)K + sseg;
    const u16* bG1 = bG0 + (size_t)64 * K;
    u16* asB = As + (w << 9);                                 // wave-uniform LDS base
    u16* bsB = Bs + (w << 9);

    const int arow = lane & 15, kg = (lane >> 4) << 3;
    const u16* aF = As + ((wr << 6) + arow) * 32 + kg;
    const u16* bF = Bs + ((wc << 6) + arow) * 32 + kg;

    for (int kt = 0; kt < K; kt += 32) {
        lds16(aG0 + kt, asB);
        lds16(aG1 + kt, asB + 2048);
        lds16(bG0 + kt, bsB);
        lds16(bG1 + kt, bsB + 2048);
        __syncthreads();   // drains vmcnt -> LDS tile ready
        bf16x8 af[4], bfr[4];
#pragma unroll
        for (int i = 0; i < 4; i++) af[i]  = *reinterpret_cast<const bf16x8*>(aF + i * 512);
#pragma unroll
        for (int i = 0; i < 4; i++) bfr[i] = *reinterpret_cast<const bf16x8*>(bF + i * 512);
#pragma unroll
        for (int i = 0; i < 4; i++)
#pragma unroll
            for (int j = 0; j < 4; j++)
                acc[i][j] = __builtin_amdgcn_mfma_f32_16x16x32_bf16(af[i], bfr[j], acc[i][j], 0, 0, 0);
        __syncthreads();   // all waves done reading before next stage overwrites
    }

    const int crow = (lane >> 4) << 2, ccol = lane & 15;
#pragma unroll
    for (int i = 0; i < 4; i++)
#pragma unroll
        for (int j = 0; j < 4; j++) {
            size_t row = m0 + (wr << 6) + (i << 4) + crow;
            size_t col = n0 + (wc << 6) + (j << 4) + ccol;
#pragma unroll
            for (int r = 0; r < 4; r++) {
                float v = acc[i][j][r];
                if (EPI == 1) { v += bias[col]; v = fmaxf(v, 0.0f); }
                if (EPI == 2) ((u16*)Cv)[(row + r) * (size_t)N + col] = f2bf(v);
                else          ((float*)Cv)[(row + r) * (size_t)N + col] = v;
            }
        }
}

// ===== KtV partials: per (bh, split of 128 rows), 64x64 fp32 outer-product accumulate =====
__global__ __launch_bounds__(256) void ktv_kernel(const u16* __restrict__ qkv,
                                                  float* __restrict__ part) {
    const int bh = blockIdx.x, split = blockIdx.y;
    const int b = bh >> 4, h = bh & 15;
    const u16* Kp = qkv + (size_t)b * 2048 * 3072 + 1024 + h * 64;
    const u16* Vp = Kp + 1024;
    __shared__ float ks[8][64], vs[8][64];
    float acc[16];
#pragma unroll
    for (int i = 0; i < 16; i++) acc[i] = 0.0f;
    const int t = threadIdx.x, r = t >> 4, c = t & 15;
    const int lr = t >> 5, lc = (t & 31) * 2;
    for (int l0 = split * 128; l0 < split * 128 + 128; l0 += 8) {
        unsigned kk = *(const unsigned*)(Kp + (size_t)(l0 + lr) * 3072 + lc);
        unsigned vv = *(const unsigned*)(Vp + (size_t)(l0 + lr) * 3072 + lc);
        ks[lr][lc] = bf2f((u16)kk); ks[lr][lc + 1] = bf2f((u16)(kk >> 16));
        vs[lr][lc] = bf2f((u16)vv); vs[lr][lc + 1] = bf2f((u16)(vv >> 16));
        __syncthreads();
#pragma unroll
        for (int i = 0; i < 8; i++) {
            float kv[4], vw[4];
#pragma unroll
            for (int a = 0; a < 4; a++) { kv[a] = ks[i][r + 16 * a]; vw[a] = vs[i][c + 16 * a]; }
#pragma unroll
            for (int a = 0; a < 4; a++)
#pragma unroll
                for (int q = 0; q < 4; q++) acc[a * 4 + q] += kv[a] * vw[q];
        }
        __syncthreads();
    }
    float* o = part + ((size_t)split * 64 + bh) * 4096;
#pragma unroll
    for (int a = 0; a < 4; a++)
#pragma unroll
        for (int q = 0; q < 4; q++) o[(r + 16 * a) * 64 + (c + 16 * q)] = acc[a * 4 + q];
}

__global__ __launch_bounds__(256) void ktv_reduce(const float* __restrict__ part,
                                                  float* __restrict__ ktv) {
    int i = blockIdx.x * 256 + threadIdx.x;  // 64*4096 = 262144
    float s = 0.0f;
#pragma unroll
    for (int sp = 0; sp < 16; sp++) s += part[(size_t)sp * 262144 + i];
    ktv[i] = s;
}

// ===== ctx = Q @ KtV / 8 -> bf16; one wave per (b,l,h) =====
__global__ __launch_bounds__(256) void ctx_kernel(const u16* __restrict__ qkv,
                                                  const float* __restrict__ ktv,
                                                  u16* __restrict__ ctx) {
    int gw = (int)((blockIdx.x * 256 + threadIdx.x) >> 6);
    int lane = threadIdx.x & 63;
    int h = gw & 15, bl = gw >> 4;       // bl in [0, 8192)
    int b = bl >> 11;
    float qv = bf2f(qkv[(size_t)bl * 3072 + h * 64 + lane]);
    const float* kt = ktv + (size_t)(b * 16 + h) * 4096;
    float s = 0.0f;
#pragma unroll
    for (int d1 = 0; d1 < 64; d1++) s += __shfl(qv, d1) * kt[d1 * 64 + lane];
    ctx[(size_t)bl * 1024 + h * 64 + lane] = f2bf(s * 0.125f);
}

// ===== layernorm of (A + B), optional bf16 copy; one block per 1024-row =====
__global__ __launch_bounds__(256) void ln_kernel(const float* __restrict__ A,
                                                 const float* __restrict__ B,
                                                 const float* __restrict__ g,
                                                 const float* __restrict__ be,
                                                 float* __restrict__ outF,
                                                 u16* __restrict__ outB) {
    __shared__ float sm[4];
    const int row = blockIdx.x, t = threadIdx.x;
    const float4 a = ((const float4*)(A + (size_t)row * 1024))[t];
    const float4 b = ((const float4*)(B + (size_t)row * 1024))[t];
    float x0 = a.x + b.x, x1 = a.y + b.y, x2 = a.z + b.z, x3 = a.w + b.w;
    float s = x0 + x1 + x2 + x3;
#pragma unroll
    for (int off = 32; off > 0; off >>= 1) s += __shfl_down(s, off);
    if ((t & 63) == 0) sm[t >> 6] = s;
    __syncthreads();
    const float mean = (sm[0] + sm[1] + sm[2] + sm[3]) * (1.0f / 1024.0f);
    __syncthreads();
    x0 -= mean; x1 -= mean; x2 -= mean; x3 -= mean;
    float s2 = x0 * x0 + x1 * x1 + x2 * x2 + x3 * x3;
#pragma unroll
    for (int off = 32; off > 0; off >>= 1) s2 += __shfl_down(s2, off);
    if ((t & 63) == 0) sm[t >> 6] = s2;
    __syncthreads();
    const float var = (sm[0] + sm[1] + sm[2] + sm[3]) * (1.0f / 1024.0f);
    const float rs = rsqrtf(var + 1e-5f);
    const float4 gv = ((const float4*)g)[t];
    const float4 bv = ((const float4*)be)[t];
    float y0 = x0 * rs * gv.x + bv.x;
    float y1 = x1 * rs * gv.y + bv.y;
    float y2 = x2 * rs * gv.z + bv.z;
    float y3 = x3 * rs * gv.w + bv.w;
    float4 o; o.x = y0; o.y = y1; o.z = y2; o.w = y3;
    ((float4*)(outF + (size_t)row * 1024))[t] = o;
    if (outB) {
        ushort4 ob; ob.x = f2bf(y0); ob.y = f2bf(y1); ob.z = f2bf(y2); ob.w = f2bf(y3);
        ((ushort4*)(outB + (size_t)row * 1024))[t] = ob;
    }
}

extern "C" void kernel_launch(void* const* d_in, const int* in_sizes, int n_in,
                              void* d_out, int out_size, void* d_ws, size_t ws_size,
                              hipStream_t stream) {
    const float* seq = (const float*)d_in[0];
    const float* Wq  = (const float*)d_in[1];
    const float* Wk  = (const float*)d_in[2];
    const float* Wv  = (const float*)d_in[3];
    const float* Wo  = (const float*)d_in[4];
    const float* g1  = (const float*)d_in[5];
    const float* b1  = (const float*)d_in[6];
    const float* Wl  = (const float*)d_in[7];
    const float* bl  = (const float*)d_in[8];
    const float* g2  = (const float*)d_in[9];
    const float* b2  = (const float*)d_in[10];

    char* ws = (char*)d_ws;
    const size_t MB = 1024 * 1024;
    float* x_f32 = (float*)(ws + 0);            // 32 MB [8192][1024]
    u16*   x_bf  = (u16*)(ws + 32 * MB);        // 16 MB
    u16*   wt    = (u16*)(ws + 48 * MB);        // 10 MB [5][1024][1024] bf16 (q,k,v,o transposed; lin direct)
    u16*   qkv   = (u16*)(ws + 58 * MB);        // 48 MB [8192][3072] bf16
    float* ktv   = (float*)(ws + 106 * MB);     // 1 MB  [64][64][64]
    u16*   ctx   = (u16*)(ws + 107 * MB);       // 16 MB [8192][1024] bf16
    float* attn  = (float*)(ws + 123 * MB);     // 32 MB [8192][1024] f32
    float* kpart = (float*)(ws + 155 * MB);     // 16 MB [16][64][4096]
    float* h1f   = (float*)(ws + 58 * MB);      // reuse qkv region
    u16*   h1b   = (u16*)(ws + 90 * MB);        // reuse qkv region
    float* ff    = (float*)(ws + 123 * MB);     // reuse attn region

    // 1. x = seq + positional
    prep_x<<<dim3(8192), dim3(256), 0, stream>>>(seq, x_f32, x_bf);
    // 2. weights -> bf16 (transposed to B^T layout for q,k,v,o)
    prep_w<<<dim3(32, 32, 5), dim3(32, 8), 0, stream>>>(Wq, Wk, Wv, Wo, Wl, wt);
    // 3. fused QKV projection: [8192,1024] @ [1024,3072] -> bf16
    gemm_bt<2><<<dim3(64 * 24), dim3(256), 0, stream>>>(x_bf, wt, qkv, nullptr, 8192, 3072, 1024);
    // 4. KtV = K^T V per (b,h), deterministic two-stage
    ktv_kernel<<<dim3(64, 16), dim3(256), 0, stream>>>(qkv, kpart);
    ktv_reduce<<<dim3(1024), dim3(256), 0, stream>>>(kpart, ktv);
    // 5. ctx = Q @ KtV / sqrt(hd)
    ctx_kernel<<<dim3(32768), dim3(256), 0, stream>>>(qkv, ktv, ctx);
    // 6. attn_out = ctx @ W_o
    gemm_bt<0><<<dim3(64 * 8), dim3(256), 0, stream>>>(ctx, wt + (size_t)3 * 1024 * 1024, attn,
                                                       nullptr, 8192, 1024, 1024);
    // 7. h1 = LN(x + attn_out)
    ln_kernel<<<dim3(8192), dim3(256), 0, stream>>>(x_f32, attn, g1, b1, h1f, h1b);
    // 8. ff = relu(h1 @ lin_W^T + lin_b)
    gemm_bt<1><<<dim3(64 * 8), dim3(256), 0, stream>>>(h1b, wt + (size_t)4 * 1024 * 1024, ff,
                                                       bl, 8192, 1024, 1024);
    // 9. out = LN(ff + h1)
    ln_kernel<<<dim3(8192), dim3(256), 0, stream>>>(ff, h1f, g2, b2, (float*)d_out, nullptr);
}

// Round 2
// 249.795 us; speedup vs baseline: 1.2535x; 1.2535x over previous
//
#include <hip/hip_runtime.h>
#include <cstdint>

typedef unsigned short u16;
typedef __bf16 bf16x8 __attribute__((ext_vector_type(8)));
typedef float f32x4 __attribute__((ext_vector_type(4)));

// ---------- bf16 helpers (RNE) ----------
__device__ __forceinline__ u16 f2bf(float f) {
    unsigned u = __float_as_uint(f);
    u += 0x7fffu + ((u >> 16) & 1u);
    return (u16)(u >> 16);
}
__device__ __forceinline__ float bf2f(u16 h) {
    return __uint_as_float(((unsigned)h) << 16);
}

// ---------- async global->LDS (16B per lane, wave-uniform LDS base) ----------
__device__ __forceinline__ void lds16(const void* g, void* l) {
    __builtin_amdgcn_global_load_lds(
        (const __attribute__((address_space(1))) void*)g,
        (__attribute__((address_space(3))) void*)l, 16, 0, 0);
}

// ================= prep: x = seq + positional; write f32 + bf16 =================
__global__ __launch_bounds__(256) void prep_x(const float* __restrict__ seq,
                                              float* __restrict__ x,
                                              u16* __restrict__ xb) {
    size_t i = (size_t)blockIdx.x * 256 + threadIdx.x;   // float4 index, 2M total
    int e4 = (int)(i & 255) * 4;
    int l  = (int)((i >> 8) & 2047);
    float4 s = ((const float4*)seq)[i];
    float v[4] = {s.x, s.y, s.z, s.w};
    const float c = -13.287712379549449f / 512.0f;       // -log2(10000)/512
#pragma unroll
    for (int j = 0; j < 4; j++) {
        int e  = e4 + j;
        int ii = e & 511;
        float st  = exp2f(c * (float)ii);
        float arg = (float)l * st;
        v[j] += (e < 512) ? sinf(arg) : cosf(arg);
    }
    float4 o; o.x = v[0]; o.y = v[1]; o.z = v[2]; o.w = v[3];
    ((float4*)x)[i] = o;
    ushort4 ob; ob.x = f2bf(v[0]); ob.y = f2bf(v[1]); ob.z = f2bf(v[2]); ob.w = f2bf(v[3]);
    ((ushort4*)xb)[i] = ob;
}

// ===== weights: mats 0..3 = transpose(W)->bf16 (B^T layout), mat 4 = lin_W direct =====
__global__ void prep_w(const float* __restrict__ wq, const float* __restrict__ wk,
                       const float* __restrict__ wv, const float* __restrict__ wo,
                       const float* __restrict__ wl, u16* __restrict__ wt) {
    int mat = blockIdx.z;
    const float* src = (mat == 0) ? wq : (mat == 1) ? wk : (mat == 2) ? wv : (mat == 3) ? wo : wl;
    u16* dst = wt + (size_t)mat * 1024 * 1024;
    int tx = threadIdx.x, ty = threadIdx.y;
    if (mat == 4) {
        int col = blockIdx.x * 32 + tx, row0 = blockIdx.y * 32;
#pragma unroll
        for (int j = 0; j < 32; j += 8)
            dst[(size_t)(row0 + ty + j) * 1024 + col] = f2bf(src[(size_t)(row0 + ty + j) * 1024 + col]);
    } else {
        __shared__ float tile[32][33];
        int col = blockIdx.x * 32 + tx, row0 = blockIdx.y * 32;
#pragma unroll
        for (int j = 0; j < 32; j += 8)
            tile[ty + j][tx] = src[(size_t)(row0 + ty + j) * 1024 + col];
        __syncthreads();
        int col2 = blockIdx.y * 32 + tx, row20 = blockIdx.x * 32;
#pragma unroll
        for (int j = 0; j < 32; j += 8)
            dst[(size_t)(row20 + ty + j) * 1024 + col2] = f2bf(tile[tx][ty + j]);
    }
}

// ================= m97-structure 128x128 bf16 GEMM, B^T input =================
// EPI: 0 = fp32 out, 1 = fp32 bias+relu out, 2 = bf16 out
// lda = A row stride (elements). bstride: if nonzero, B^T is batched per 2048
// A-rows: Bt_eff = Bt + (m0>>11)*bstride.
template <int EPI>
__global__ __launch_bounds__(256) void gemm_bt(const u16* __restrict__ A,   // [M,·] bf16
                                               const u16* __restrict__ Bt,  // [N,K] bf16
                                               void* __restrict__ Cv,
                                               const float* __restrict__ bias,
                                               int M, int N, int K, int lda,
                                               size_t bstride) {
    __shared__ __align__(16) u16 As[128 * 32];
    __shared__ __align__(16) u16 Bs[128 * 32];
    const int t = threadIdx.x;
    const int ntn = N >> 7;
    const int tm = blockIdx.x / ntn, tn = blockIdx.x % ntn;
    const size_t m0 = (size_t)tm << 7, n0 = (size_t)tn << 7;
    const int w = t >> 6, lane = t & 63;
    const int wr = w >> 1, wc = w & 1;
    const u16* Bt_e = Bt + (bstride ? (m0 >> 11) * bstride : 0);

    f32x4 acc[4][4];
#pragma unroll
    for (int i = 0; i < 4; i++)
#pragma unroll
        for (int j = 0; j < 4; j++)
#pragma unroll
            for (int r = 0; r < 4; r++) acc[i][j][r] = 0.0f;

    const int srow = t >> 2, sseg = (t & 3) << 3;            // staging: row, 8-elem segment
    const u16* aG0 = A + (m0 + srow) * (size_t)lda + sseg;
    const u16* aG1 = aG0 + (size_t)64 * lda;
    const u16* bG0 = Bt_e + (n0 + srow) * (size_t)K + sseg;
    const u16* bG1 = bG0 + (size_t)64 * K;
    u16* asB = As + (w << 9);                                 // wave-uniform LDS base
    u16* bsB = Bs + (w << 9);

    const int arow = lane & 15, kg = (lane >> 4) << 3;
    const u16* aF = As + ((wr << 6) + arow) * 32 + kg;
    const u16* bF = Bs + ((wc << 6) + arow) * 32 + kg;

    for (int kt = 0; kt < K; kt += 32) {
        lds16(aG0 + kt, asB);
        lds16(aG1 + kt, asB + 2048);
        lds16(bG0 + kt, bsB);
        lds16(bG1 + kt, bsB + 2048);
        __syncthreads();   // drains vmcnt -> LDS tile ready
        bf16x8 af[4], bfr[4];
#pragma unroll
        for (int i = 0; i < 4; i++) af[i]  = *reinterpret_cast<const bf16x8*>(aF + i * 512);
#pragma unroll
        for (int i = 0; i < 4; i++) bfr[i] = *reinterpret_cast<const bf16x8*>(bF + i * 512);
#pragma unroll
        for (int i = 0; i < 4; i++)
#pragma unroll
            for (int j = 0; j < 4; j++)
                acc[i][j] = __builtin_amdgcn_mfma_f32_16x16x32_bf16(af[i], bfr[j], acc[i][j], 0, 0, 0);
        __syncthreads();   // all waves done reading before next stage overwrites
    }

    const int crow = (lane >> 4) << 2, ccol = lane & 15;
#pragma unroll
    for (int i = 0; i < 4; i++)
#pragma unroll
        for (int j = 0; j < 4; j++) {
            size_t row = m0 + (wr << 6) + (i << 4) + crow;
            size_t col = n0 + (wc << 6) + (j << 4) + ccol;
#pragma unroll
            for (int r = 0; r < 4; r++) {
                float v = acc[i][j][r];
                if (EPI == 1) { v += bias[col]; v = fmaxf(v, 0.0f); }
                if (EPI == 2) ((u16*)Cv)[(row + r) * (size_t)N + col] = f2bf(v);
                else          ((float*)Cv)[(row + r) * (size_t)N + col] = v;
            }
        }
}

// ===== KtV partials: per (bh, split of 128 rows), 64x64 fp32 outer-product accumulate =====
__global__ __launch_bounds__(256) void ktv_kernel(const u16* __restrict__ qkv,
                                                  float* __restrict__ part) {
    const int bh = blockIdx.x, split = blockIdx.y;
    const int b = bh >> 4, h = bh & 15;
    const u16* Kp = qkv + (size_t)b * 2048 * 3072 + 1024 + h * 64;
    const u16* Vp = Kp + 1024;
    __shared__ float ks[8][64], vs[8][64];
    float acc[16];
#pragma unroll
    for (int i = 0; i < 16; i++) acc[i] = 0.0f;
    const int t = threadIdx.x, r = t >> 4, c = t & 15;
    const int lr = t >> 5, lc = (t & 31) * 2;
    for (int l0 = split * 128; l0 < split * 128 + 128; l0 += 8) {
        unsigned kk = *(const unsigned*)(Kp + (size_t)(l0 + lr) * 3072 + lc);
        unsigned vv = *(const unsigned*)(Vp + (size_t)(l0 + lr) * 3072 + lc);
        ks[lr][lc] = bf2f((u16)kk); ks[lr][lc + 1] = bf2f((u16)(kk >> 16));
        vs[lr][lc] = bf2f((u16)vv); vs[lr][lc + 1] = bf2f((u16)(vv >> 16));
        __syncthreads();
#pragma unroll
        for (int i = 0; i < 8; i++) {
            float kv[4], vw[4];
#pragma unroll
            for (int a = 0; a < 4; a++) { kv[a] = ks[i][r + 16 * a]; vw[a] = vs[i][c + 16 * a]; }
#pragma unroll
            for (int a = 0; a < 4; a++)
#pragma unroll
                for (int q = 0; q < 4; q++) acc[a * 4 + q] += kv[a] * vw[q];
        }
        __syncthreads();
    }
    float* o = part + ((size_t)split * 64 + bh) * 4096;
#pragma unroll
    for (int a = 0; a < 4; a++)
#pragma unroll
        for (int q = 0; q < 4; q++) o[(r + 16 * a) * 64 + (c + 16 * q)] = acc[a * 4 + q];
}

__global__ __launch_bounds__(256) void ktv_reduce(const float* __restrict__ part,
                                                  float* __restrict__ ktv) {
    int i = blockIdx.x * 256 + threadIdx.x;  // 64*4096 = 262144
    float s = 0.0f;
#pragma unroll
    for (int sp = 0; sp < 16; sp++) s += part[(size_t)sp * 262144 + i];
    ktv[i] = s;
}

// ===== W'^T_b[n][h*64+i] = sum_j (KtV_bh[i][j]/8) * Wo[h*64+j][n]  -> bf16 =====
// One thread per n; KtV reads are wave-uniform -> scalar loads; 4096 v_fmac/thread.
__global__ __launch_bounds__(256) void wprime_kernel(const float* __restrict__ ktv,
                                                     const float* __restrict__ Wo,
                                                     u16* __restrict__ wp) {
    const int n = blockIdx.x * 256 + threadIdx.x;   // blockIdx.x in [0,4)
    const int h = blockIdx.y, b = blockIdx.z;
    const float* kt = ktv + ((size_t)(b * 16 + h) << 12);
    float acc[64];
#pragma unroll
    for (int i = 0; i < 64; i++) acc[i] = 0.0f;
    for (int j = 0; j < 64; j++) {
        float w = Wo[(size_t)(h * 64 + j) * 1024 + n];
#pragma unroll
        for (int i = 0; i < 64; i++) acc[i] += kt[i * 64 + j] * w;
    }
    u16* o = wp + ((size_t)b << 20) + (size_t)n * 1024 + h * 64;
    u16 ob[64];
#pragma unroll
    for (int i = 0; i < 64; i++) ob[i] = f2bf(acc[i] * 0.125f);
#pragma unroll
    for (int i = 0; i < 8; i++)
        ((uint4*)o)[i] = ((const uint4*)ob)[i];
}

// ===== layernorm of (A + B), optional bf16 copy; one block per 1024-row =====
__global__ __launch_bounds__(256) void ln_kernel(const float* __restrict__ A,
                                                 const float* __restrict__ B,
                                                 const float* __restrict__ g,
                                                 const float* __restrict__ be,
                                                 float* __restrict__ outF,
                                                 u16* __restrict__ outB) {
    __shared__ float sm[4];
    const int row = blockIdx.x, t = threadIdx.x;
    const float4 a = ((const float4*)(A + (size_t)row * 1024))[t];
    const float4 b = ((const float4*)(B + (size_t)row * 1024))[t];
    float x0 = a.x + b.x, x1 = a.y + b.y, x2 = a.z + b.z, x3 = a.w + b.w;
    float s = x0 + x1 + x2 + x3;
#pragma unroll
    for (int off = 32; off > 0; off >>= 1) s += __shfl_down(s, off);
    if ((t & 63) == 0) sm[t >> 6] = s;
    __syncthreads();
    const float mean = (sm[0] + sm[1] + sm[2] + sm[3]) * (1.0f / 1024.0f);
    __syncthreads();
    x0 -= mean; x1 -= mean; x2 -= mean; x3 -= mean;
    float s2 = x0 * x0 + x1 * x1 + x2 * x2 + x3 * x3;
#pragma unroll
    for (int off = 32; off > 0; off >>= 1) s2 += __shfl_down(s2, off);
    if ((t & 63) == 0) sm[t >> 6] = s2;
    __syncthreads();
    const float var = (sm[0] + sm[1] + sm[2] + sm[3]) * (1.0f / 1024.0f);
    const float rs = rsqrtf(var + 1e-5f);
    const float4 gv = ((const float4*)g)[t];
    const float4 bv = ((const float4*)be)[t];
    float y0 = x0 * rs * gv.x + bv.x;
    float y1 = x1 * rs * gv.y + bv.y;
    float y2 = x2 * rs * gv.z + bv.z;
    float y3 = x3 * rs * gv.w + bv.w;
    float4 o; o.x = y0; o.y = y1; o.z = y2; o.w = y3;
    ((float4*)(outF + (size_t)row * 1024))[t] = o;
    if (outB) {
        ushort4 ob; ob.x = f2bf(y0); ob.y = f2bf(y1); ob.z = f2bf(y2); ob.w = f2bf(y3);
        ((ushort4*)(outB + (size_t)row * 1024))[t] = ob;
    }
}

extern "C" void kernel_launch(void* const* d_in, const int* in_sizes, int n_in,
                              void* d_out, int out_size, void* d_ws, size_t ws_size,
                              hipStream_t stream) {
    const float* seq = (const float*)d_in[0];
    const float* Wq  = (const float*)d_in[1];
    const float* Wk  = (const float*)d_in[2];
    const float* Wv  = (const float*)d_in[3];
    const float* Wo  = (const float*)d_in[4];
    const float* g1  = (const float*)d_in[5];
    const float* b1  = (const float*)d_in[6];
    const float* Wl  = (const float*)d_in[7];
    const float* bl  = (const float*)d_in[8];
    const float* g2  = (const float*)d_in[9];
    const float* b2  = (const float*)d_in[10];

    char* ws = (char*)d_ws;
    const size_t MB = 1024 * 1024;
    float* x_f32 = (float*)(ws + 0);            // 32 MB [8192][1024]
    u16*   x_bf  = (u16*)(ws + 32 * MB);        // 16 MB
    u16*   wt    = (u16*)(ws + 48 * MB);        // 10 MB [5][1024][1024] bf16
    u16*   qkv   = (u16*)(ws + 58 * MB);        // 48 MB [8192][3072] bf16
    float* ktv   = (float*)(ws + 106 * MB);     // 1 MB  [64][64][64]
    float* attn  = (float*)(ws + 107 * MB);     // 32 MB [8192][1024] f32
    u16*   wpr   = (u16*)(ws + 139 * MB);       // 8 MB  [4][1024][1024] bf16 (W'^T per batch)
    float* kpart = (float*)(ws + 147 * MB);     // 16 MB [16][64][4096]
    float* h1f   = (float*)(ws + 58 * MB);      // reuse qkv region (free after attn GEMM)
    u16*   h1b   = (u16*)(ws + 90 * MB);        // reuse qkv region
    float* ff    = (float*)(ws + 107 * MB);     // reuse attn region

    // 1. x = seq + positional
    prep_x<<<dim3(8192), dim3(256), 0, stream>>>(seq, x_f32, x_bf);
    // 2. weights -> bf16 (B^T layout for q,k,v,o; lin_W direct)
    prep_w<<<dim3(32, 32, 5), dim3(32, 8), 0, stream>>>(Wq, Wk, Wv, Wo, Wl, wt);
    // 3. fused QKV projection: [8192,1024] @ [1024,3072] -> bf16
    gemm_bt<2><<<dim3(64 * 24), dim3(256), 0, stream>>>(x_bf, wt, qkv, nullptr,
                                                        8192, 3072, 1024, 1024, 0);
    // 4. KtV = K^T V per (b,h), deterministic two-stage
    ktv_kernel<<<dim3(64, 16), dim3(256), 0, stream>>>(qkv, kpart);
    ktv_reduce<<<dim3(1024), dim3(256), 0, stream>>>(kpart, ktv);
    // 5. W'^T_b = (blockdiag(KtV_b)/8 @ W_o)^T  -> bf16
    wprime_kernel<<<dim3(4, 16, 4), dim3(256), 0, stream>>>(ktv, Wo, wpr);
    // 6. attn_out = Q @ W'_b  (Q = strided view of qkv, lda=3072; B batched per 2048 rows)
    gemm_bt<0><<<dim3(64 * 8), dim3(256), 0, stream>>>(qkv, wpr, attn, nullptr,
                                                       8192, 1024, 1024, 3072,
                                                       (size_t)1024 * 1024);
    // 7. h1 = LN(x + attn_out)
    ln_kernel<<<dim3(8192), dim3(256), 0, stream>>>(x_f32, attn, g1, b1, h1f, h1b);
    // 8. ff = relu(h1 @ lin_W^T + lin_b)
    gemm_bt<1><<<dim3(64 * 8), dim3(256), 0, stream>>>(h1b, wt + (size_t)4 * 1024 * 1024, ff,
                                                       bl, 8192, 1024, 1024, 1024, 0);
    // 9. out = LN(ff + h1)
    ln_kernel<<<dim3(8192), dim3(256), 0, stream>>>(ff, h1f, g2, b2, (float*)d_out, nullptr);
}

// Round 3
// 223.520 us; speedup vs baseline: 1.4008x; 1.1175x over previous
//
#include <hip/hip_runtime.h>
#include <cstdint>

typedef unsigned short u16;
typedef __bf16 bf16x8 __attribute__((ext_vector_type(8)));
typedef float f32x4 __attribute__((ext_vector_type(4)));

// ---------- bf16 helpers (RNE) ----------
__device__ __forceinline__ u16 f2bf(float f) {
    unsigned u = __float_as_uint(f);
    u += 0x7fffu + ((u >> 16) & 1u);
    return (u16)(u >> 16);
}
__device__ __forceinline__ float bf2f(u16 h) {
    return __uint_as_float(((unsigned)h) << 16);
}

// ---------- async global->LDS (16B per lane, wave-uniform LDS base) ----------
__device__ __forceinline__ void lds16(const void* g, void* l) {
    __builtin_amdgcn_global_load_lds(
        (const __attribute__((address_space(1))) void*)g,
        (__attribute__((address_space(3))) void*)l, 16, 0, 0);
}

// ================= prep: x = seq + positional; write f32 + bf16 =================
__global__ __launch_bounds__(256) void prep_x(const float* __restrict__ seq,
                                              float* __restrict__ x,
                                              u16* __restrict__ xb) {
    size_t i = (size_t)blockIdx.x * 256 + threadIdx.x;   // float4 index, 2M total
    int e4 = (int)(i & 255) * 4;
    int l  = (int)((i >> 8) & 2047);
    float4 s = ((const float4*)seq)[i];
    float v[4] = {s.x, s.y, s.z, s.w};
    const float c = -13.287712379549449f / 512.0f;       // -log2(10000)/512
#pragma unroll
    for (int j = 0; j < 4; j++) {
        int e  = e4 + j;
        int ii = e & 511;
        float st  = exp2f(c * (float)ii);
        float arg = (float)l * st;
        v[j] += (e < 512) ? sinf(arg) : cosf(arg);
    }
    float4 o; o.x = v[0]; o.y = v[1]; o.z = v[2]; o.w = v[3];
    ((float4*)x)[i] = o;
    ushort4 ob; ob.x = f2bf(v[0]); ob.y = f2bf(v[1]); ob.z = f2bf(v[2]); ob.w = f2bf(v[3]);
    ((ushort4*)xb)[i] = ob;
}

// ===== weights: mats 0..3 = transpose(W)->bf16 (B^T layout), mat 4 = lin_W direct =====
__global__ void prep_w(const float* __restrict__ wq, const float* __restrict__ wk,
                       const float* __restrict__ wv, const float* __restrict__ wo,
                       const float* __restrict__ wl, u16* __restrict__ wt) {
    int mat = blockIdx.z;
    const float* src = (mat == 0) ? wq : (mat == 1) ? wk : (mat == 2) ? wv : (mat == 3) ? wo : wl;
    u16* dst = wt + (size_t)mat * 1024 * 1024;
    int tx = threadIdx.x, ty = threadIdx.y;
    if (mat == 4) {
        int col = blockIdx.x * 32 + tx, row0 = blockIdx.y * 32;
#pragma unroll
        for (int j = 0; j < 32; j += 8)
            dst[(size_t)(row0 + ty + j) * 1024 + col] = f2bf(src[(size_t)(row0 + ty + j) * 1024 + col]);
    } else {
        __shared__ float tile[32][33];
        int col = blockIdx.x * 32 + tx, row0 = blockIdx.y * 32;
#pragma unroll
        for (int j = 0; j < 32; j += 8)
            tile[ty + j][tx] = src[(size_t)(row0 + ty + j) * 1024 + col];
        __syncthreads();
        int col2 = blockIdx.y * 32 + tx, row20 = blockIdx.x * 32;
#pragma unroll
        for (int j = 0; j < 32; j += 8)
            dst[(size_t)(row20 + ty + j) * 1024 + col2] = f2bf(tile[tx][ty + j]);
    }
}

// ============ deep-pipelined 128x256 bf16 GEMM (BK=64, dbuf, counted vmcnt) ============
// C = A @ Bt^T.  A: [M, lda] bf16 (rows m0..m0+127 used).  Bt: [N, K] bf16.
// EPI: 0 = fp32 out, 1 = fp32 bias+relu out, 2 = bf16 out.
// bstride: if nonzero, Bt is batched per 2048 A-rows (Bt_eff = Bt + (m0>>11)*bstride).
//
// LDS layout per buffer (48 KB): A-unit 16 KB (128 rows x 64 k, bf16), then
// B-units 32 KB (256 rows x 64 k). Element (row,kseg8) lives at byte
// row*128 + ((kseg ^ (row&7))<<4)  -> conflict-free ds_read_b128 column-slices (T2).
// global_load_lds writes linearly; the XOR is applied to the per-lane GLOBAL source
// (rule #21: linear dest + inverse-swizzled source + swizzled read).
template <int EPI>
__global__ __launch_bounds__(512) void gemm8p(const u16* __restrict__ A,
                                              const u16* __restrict__ Bt,
                                              void* __restrict__ Cv,
                                              const float* __restrict__ bias,
                                              int N, int K, int lda, size_t bstride) {
    __shared__ __align__(16) u16 lds[49152];   // 96 KB = 2 x 24576 u16
    const int t = threadIdx.x;
    const int ntn = N >> 8;
    const int nwg = gridDim.x;                 // must be % 8 == 0 (bijective XCD swizzle)
    int bid = (int)blockIdx.x;
    bid = (bid & 7) * (nwg >> 3) + (bid >> 3);
    const int tm = bid / ntn, tn = bid - tm * ntn;
    const size_t m0 = (size_t)tm << 7, n0 = (size_t)tn << 8;
    const int w = t >> 6, lane = t & 63;
    const int wr = w >> 2, wc = w & 3;         // 2 (M) x 4 (N) waves
    const u16* Bt_e = Bt + (bstride ? (m0 >> 11) * bstride : 0);

    // ---- staging: thread t covers lds-linear slots s = {t, 512+t} of each unit ----
    // slot s -> row r = s>>3, stored kseg-slot = s&7, source kseg = (s&7)^(r&7)
    const int r0 = t >> 3;                      // 0..63 (i=1 adds 64; (r&7) unchanged)
    const int ksrc = (t & 7) ^ (r0 & 7);
    const u16* sA0 = A + (m0 + r0) * (size_t)lda + ksrc * 8;
    const u16* sA1 = sA0 + (size_t)64 * lda;
    const u16* sB0 = Bt_e + (n0 + r0) * (size_t)K + ksrc * 8;
    const u16* sB1 = sB0 + (size_t)64 * K;
    const u16* sB2 = sB0 + (size_t)128 * K;
    const u16* sB3 = sB0 + (size_t)192 * K;
    u16* dstW = lds + (w << 9);                 // wave-uniform; HW adds lane*16B

    // ---- fragment read offsets (u16 units) ----
    const int ao = ((wr << 6) | (lane & 15)) << 6;            // A row * 64
    const int bo = 8192 + ((((wc << 6) | (lane & 15))) << 6); // B region + n-row * 64
    const int kx = lane & 7;
    const int ks0 = (((lane >> 4) ^ kx) << 3);
    const int ks1 = (((4 + (lane >> 4)) ^ kx) << 3);

    f32x4 acc[4][4];
#pragma unroll
    for (int i = 0; i < 4; i++)
#pragma unroll
        for (int j = 0; j < 4; j++)
#pragma unroll
            for (int r = 0; r < 4; r++) acc[i][j][r] = 0.0f;

    const int NT = K >> 6;
    // prologue: stage kt=0 into buf0 (6 loads/thread)
    lds16(sA0, dstW);          lds16(sA1, dstW + 4096);
    lds16(sB0, dstW + 8192);   lds16(sB1, dstW + 12288);
    lds16(sB2, dstW + 16384);  lds16(sB3, dstW + 20480);

    for (int kt = 0; kt < NT; kt++) {
        const int b = kt & 1;
        asm volatile("" ::: "memory");         // keep prev reads above next stage
        if (kt + 1 < NT) {
            const size_t ko = (size_t)(kt + 1) << 6;
            u16* d = dstW + (b ^ 1) * 24576;
            lds16(sA0 + ko, d);          lds16(sA1 + ko, d + 4096);
            lds16(sB0 + ko, d + 8192);   lds16(sB1 + ko, d + 12288);
            lds16(sB2 + ko, d + 16384);  lds16(sB3 + ko, d + 20480);
            // queue: [kt's 6 (oldest), kt+1's 6] -> wait own kt loads retired,
            // keep kt+1's prefetch in flight across the barrier (T4: never 0 in-loop)
            asm volatile("s_waitcnt vmcnt(6)" ::: "memory");
        } else {
            asm volatile("s_waitcnt vmcnt(0)" ::: "memory");
        }
        __builtin_amdgcn_s_barrier();          // all waves' kt loads retired -> tile ready
        asm volatile("" ::: "memory");         // no ds_read hoists above the barrier
        const u16* Lb = lds + b * 24576;
#pragma unroll
        for (int kc = 0; kc < 2; kc++) {
            const int ksl = kc ? ks1 : ks0;
            bf16x8 af[4], bfr[4];
#pragma unroll
            for (int i = 0; i < 4; i++)
                af[i] = *reinterpret_cast<const bf16x8*>(Lb + ao + i * 1024 + ksl);
#pragma unroll
            for (int j = 0; j < 4; j++)
                bfr[j] = *reinterpret_cast<const bf16x8*>(Lb + bo + j * 1024 + ksl);
            __builtin_amdgcn_s_setprio(1);
#pragma unroll
            for (int i = 0; i < 4; i++)
#pragma unroll
                for (int j = 0; j < 4; j++)
                    acc[i][j] = __builtin_amdgcn_mfma_f32_16x16x32_bf16(af[i], bfr[j], acc[i][j], 0, 0, 0);
            __builtin_amdgcn_s_setprio(0);
        }
        asm volatile("" ::: "memory");
        __builtin_amdgcn_s_barrier();          // all waves done reading buf b
    }

    // ---- epilogue ----
    const int crow = (lane >> 4) << 2, ccol = lane & 15;
#pragma unroll
    for (int i = 0; i < 4; i++)
#pragma unroll
        for (int j = 0; j < 4; j++) {
            size_t row = m0 + (wr << 6) + (i << 4) + crow;
            size_t col = n0 + (wc << 6) + (j << 4) + ccol;
#pragma unroll
            for (int r = 0; r < 4; r++) {
                float v = acc[i][j][r];
                if (EPI == 1) { v += bias[col]; v = fmaxf(v, 0.0f); }
                if (EPI == 2) ((u16*)Cv)[(row + r) * (size_t)N + col] = f2bf(v);
                else          ((float*)Cv)[(row + r) * (size_t)N + col] = v;
            }
        }
}

// ===== KtV partials: per (bh, split of 128 rows), 64x64 fp32 outer-product accumulate =====
__global__ __launch_bounds__(256) void ktv_kernel(const u16* __restrict__ qkv,
                                                  float* __restrict__ part) {
    const int bh = blockIdx.x, split = blockIdx.y;
    const int b = bh >> 4, h = bh & 15;
    const u16* Kp = qkv + (size_t)b * 2048 * 3072 + 1024 + h * 64;
    const u16* Vp = Kp + 1024;
    __shared__ float ks[8][64], vs[8][64];
    float acc[16];
#pragma unroll
    for (int i = 0; i < 16; i++) acc[i] = 0.0f;
    const int t = threadIdx.x, r = t >> 4, c = t & 15;
    const int lr = t >> 5, lc = (t & 31) * 2;
    for (int l0 = split * 128; l0 < split * 128 + 128; l0 += 8) {
        unsigned kk = *(const unsigned*)(Kp + (size_t)(l0 + lr) * 3072 + lc);
        unsigned vv = *(const unsigned*)(Vp + (size_t)(l0 + lr) * 3072 + lc);
        ks[lr][lc] = bf2f((u16)kk); ks[lr][lc + 1] = bf2f((u16)(kk >> 16));
        vs[lr][lc] = bf2f((u16)vv); vs[lr][lc + 1] = bf2f((u16)(vv >> 16));
        __syncthreads();
#pragma unroll
        for (int i = 0; i < 8; i++) {
            float kv[4], vw[4];
#pragma unroll
            for (int a = 0; a < 4; a++) { kv[a] = ks[i][r + 16 * a]; vw[a] = vs[i][c + 16 * a]; }
#pragma unroll
            for (int a = 0; a < 4; a++)
#pragma unroll
                for (int q = 0; q < 4; q++) acc[a * 4 + q] += kv[a] * vw[q];
        }
        __syncthreads();
    }
    float* o = part + ((size_t)split * 64 + bh) * 4096;
#pragma unroll
    for (int a = 0; a < 4; a++)
#pragma unroll
        for (int q = 0; q < 4; q++) o[(r + 16 * a) * 64 + (c + 16 * q)] = acc[a * 4 + q];
}

__global__ __launch_bounds__(256) void ktv_reduce(const float* __restrict__ part,
                                                  float* __restrict__ ktv) {
    int i = blockIdx.x * 256 + threadIdx.x;  // 64*4096 = 262144
    float s = 0.0f;
#pragma unroll
    for (int sp = 0; sp < 16; sp++) s += part[(size_t)sp * 262144 + i];
    ktv[i] = s;
}

// ===== W'^T_b[n][h*64+i] = sum_j (KtV_bh[i][j]/8) * Wo[h*64+j][n]  -> bf16 =====
__global__ __launch_bounds__(256) void wprime_kernel(const float* __restrict__ ktv,
                                                     const float* __restrict__ Wo,
                                                     u16* __restrict__ wp) {
    const int n = blockIdx.x * 256 + threadIdx.x;   // blockIdx.x in [0,4)
    const int h = blockIdx.y, b = blockIdx.z;
    const float* kt = ktv + ((size_t)(b * 16 + h) << 12);
    float acc[64];
#pragma unroll
    for (int i = 0; i < 64; i++) acc[i] = 0.0f;
    for (int j = 0; j < 64; j++) {
        float w = Wo[(size_t)(h * 64 + j) * 1024 + n];
#pragma unroll
        for (int i = 0; i < 64; i++) acc[i] += kt[i * 64 + j] * w;
    }
    u16* o = wp + ((size_t)b << 20) + (size_t)n * 1024 + h * 64;
    u16 ob[64];
#pragma unroll
    for (int i = 0; i < 64; i++) ob[i] = f2bf(acc[i] * 0.125f);
#pragma unroll
    for (int i = 0; i < 8; i++)
        ((uint4*)o)[i] = ((const uint4*)ob)[i];
}

// ===== layernorm of (A + B), optional bf16 copy; one block per 1024-row =====
__global__ __launch_bounds__(256) void ln_kernel(const float* __restrict__ A,
                                                 const float* __restrict__ B,
                                                 const float* __restrict__ g,
                                                 const float* __restrict__ be,
                                                 float* __restrict__ outF,
                                                 u16* __restrict__ outB) {
    __shared__ float sm[4];
    const int row = blockIdx.x, t = threadIdx.x;
    const float4 a = ((const float4*)(A + (size_t)row * 1024))[t];
    const float4 b = ((const float4*)(B + (size_t)row * 1024))[t];
    float x0 = a.x + b.x, x1 = a.y + b.y, x2 = a.z + b.z, x3 = a.w + b.w;
    float s = x0 + x1 + x2 + x3;
#pragma unroll
    for (int off = 32; off > 0; off >>= 1) s += __shfl_down(s, off);
    if ((t & 63) == 0) sm[t >> 6] = s;
    __syncthreads();
    const float mean = (sm[0] + sm[1] + sm[2] + sm[3]) * (1.0f / 1024.0f);
    __syncthreads();
    x0 -= mean; x1 -= mean; x2 -= mean; x3 -= mean;
    float s2 = x0 * x0 + x1 * x1 + x2 * x2 + x3 * x3;
#pragma unroll
    for (int off = 32; off > 0; off >>= 1) s2 += __shfl_down(s2, off);
    if ((t & 63) == 0) sm[t >> 6] = s2;
    __syncthreads();
    const float var = (sm[0] + sm[1] + sm[2] + sm[3]) * (1.0f / 1024.0f);
    const float rs = rsqrtf(var + 1e-5f);
    const float4 gv = ((const float4*)g)[t];
    const float4 bv = ((const float4*)be)[t];
    float y0 = x0 * rs * gv.x + bv.x;
    float y1 = x1 * rs * gv.y + bv.y;
    float y2 = x2 * rs * gv.z + bv.z;
    float y3 = x3 * rs * gv.w + bv.w;
    float4 o; o.x = y0; o.y = y1; o.z = y2; o.w = y3;
    ((float4*)(outF + (size_t)row * 1024))[t] = o;
    if (outB) {
        ushort4 ob; ob.x = f2bf(y0); ob.y = f2bf(y1); ob.z = f2bf(y2); ob.w = f2bf(y3);
        ((ushort4*)(outB + (size_t)row * 1024))[t] = ob;
    }
}

extern "C" void kernel_launch(void* const* d_in, const int* in_sizes, int n_in,
                              void* d_out, int out_size, void* d_ws, size_t ws_size,
                              hipStream_t stream) {
    const float* seq = (const float*)d_in[0];
    const float* Wq  = (const float*)d_in[1];
    const float* Wk  = (const float*)d_in[2];
    const float* Wv  = (const float*)d_in[3];
    const float* Wo  = (const float*)d_in[4];
    const float* g1  = (const float*)d_in[5];
    const float* b1  = (const float*)d_in[6];
    const float* Wl  = (const float*)d_in[7];
    const float* bl  = (const float*)d_in[8];
    const float* g2  = (const float*)d_in[9];
    const float* b2  = (const float*)d_in[10];

    char* ws = (char*)d_ws;
    const size_t MB = 1024 * 1024;
    float* x_f32 = (float*)(ws + 0);            // 32 MB [8192][1024]
    u16*   x_bf  = (u16*)(ws + 32 * MB);        // 16 MB
    u16*   wt    = (u16*)(ws + 48 * MB);        // 10 MB [5][1024][1024] bf16
    u16*   qkv   = (u16*)(ws + 58 * MB);        // 48 MB [8192][3072] bf16
    float* ktv   = (float*)(ws + 106 * MB);     // 1 MB  [64][64][64]
    float* attn  = (float*)(ws + 107 * MB);     // 32 MB [8192][1024] f32
    u16*   wpr   = (u16*)(ws + 139 * MB);       // 8 MB  [4][1024][1024] bf16 (W'^T per batch)
    float* kpart = (float*)(ws + 147 * MB);     // 16 MB [16][64][4096]
    float* h1f   = (float*)(ws + 58 * MB);      // reuse qkv region (free after attn GEMM)
    u16*   h1b   = (u16*)(ws + 90 * MB);        // reuse qkv region
    float* ff    = (float*)(ws + 107 * MB);     // reuse attn region

    // 1. x = seq + positional
    prep_x<<<dim3(8192), dim3(256), 0, stream>>>(seq, x_f32, x_bf);
    // 2. weights -> bf16 (B^T layout for q,k,v,o; lin_W direct)
    prep_w<<<dim3(32, 32, 5), dim3(32, 8), 0, stream>>>(Wq, Wk, Wv, Wo, Wl, wt);
    // 3. fused QKV projection: [8192,1024] @ [1024,3072] -> bf16   (grid 64x12=768, %8==0)
    gemm8p<2><<<dim3(768), dim3(512), 0, stream>>>(x_bf, wt, qkv, nullptr,
                                                   3072, 1024, 1024, 0);
    // 4. KtV = K^T V per (b,h), deterministic two-stage
    ktv_kernel<<<dim3(64, 16), dim3(256), 0, stream>>>(qkv, kpart);
    ktv_reduce<<<dim3(1024), dim3(256), 0, stream>>>(kpart, ktv);
    // 5. W'^T_b = (blockdiag(KtV_b)/8 @ W_o)^T  -> bf16
    wprime_kernel<<<dim3(4, 16, 4), dim3(256), 0, stream>>>(ktv, Wo, wpr);
    // 6. attn_out = Q @ W'_b  (Q strided in qkv, lda=3072; B batched per 2048 rows; grid 256)
    gemm8p<0><<<dim3(256), dim3(512), 0, stream>>>(qkv, wpr, attn, nullptr,
                                                   1024, 1024, 3072, (size_t)1024 * 1024);
    // 7. h1 = LN(x + attn_out)
    ln_kernel<<<dim3(8192), dim3(256), 0, stream>>>(x_f32, attn, g1, b1, h1f, h1b);
    // 8. ff = relu(h1 @ lin_W^T + lin_b)   (grid 256)
    gemm8p<1><<<dim3(256), dim3(512), 0, stream>>>(h1b, wt + (size_t)4 * 1024 * 1024, ff,
                                                   bl, 1024, 1024, 1024, 0);
    // 9. out = LN(ff + h1)
    ln_kernel<<<dim3(8192), dim3(256), 0, stream>>>(ff, h1f, g2, b2, (float*)d_out, nullptr);
}

// Round 4
// 212.561 us; speedup vs baseline: 1.4730x; 1.0516x over previous
//
#include <hip/hip_runtime.h>
#include <cstdint>

typedef unsigned short u16;
typedef __bf16 bf16x8 __attribute__((ext_vector_type(8)));
typedef float f32x4 __attribute__((ext_vector_type(4)));

// ---------- bf16 helpers (RNE) ----------
__device__ __forceinline__ u16 f2bf(float f) {
    unsigned u = __float_as_uint(f);
    u += 0x7fffu + ((u >> 16) & 1u);
    return (u16)(u >> 16);
}
__device__ __forceinline__ float bf2f(u16 h) {
    return __uint_as_float(((unsigned)h) << 16);
}

// ---------- async global->LDS (16B per lane, wave-uniform LDS base) ----------
__device__ __forceinline__ void lds16(const void* g, void* l) {
    __builtin_amdgcn_global_load_lds(
        (const __attribute__((address_space(1))) void*)g,
        (__attribute__((address_space(3))) void*)l, 16, 0, 0);
}

// ---------- positional encoding term for element e of row l ----------
__device__ __forceinline__ float pos_term(int l, int e) {
    const float c = -13.287712379549449f / 512.0f;       // -log2(10000)/512
    int ii = e & 511;
    float st  = exp2f(c * (float)ii);
    float arg = (float)l * st;
    return (e < 512) ? sinf(arg) : cosf(arg);
}

// ================= prep: x_bf = bf16(seq + positional) =================
__global__ __launch_bounds__(256) void prep_x(const float* __restrict__ seq,
                                              u16* __restrict__ xb) {
    size_t i = (size_t)blockIdx.x * 256 + threadIdx.x;   // float4 index, 2M total
    int e4 = (int)(i & 255) * 4;
    int l  = (int)((i >> 8) & 2047);
    float4 s = ((const float4*)seq)[i];
    float v[4] = {s.x, s.y, s.z, s.w};
#pragma unroll
    for (int j = 0; j < 4; j++) v[j] += pos_term(l, e4 + j);
    ushort4 ob; ob.x = f2bf(v[0]); ob.y = f2bf(v[1]); ob.z = f2bf(v[2]); ob.w = f2bf(v[3]);
    ((ushort4*)xb)[i] = ob;
}

// ===== weights -> bf16: mat0 = Wq direct, mat1 = Wk^T, mat2 = Wv^T, mat3 = Wl direct =====
__global__ void prep_w(const float* __restrict__ wq, const float* __restrict__ wk,
                       const float* __restrict__ wv, const float* __restrict__ wl,
                       u16* __restrict__ wt) {
    int mat = blockIdx.z;
    const float* src = (mat == 0) ? wq : (mat == 1) ? wk : (mat == 2) ? wv : wl;
    u16* dst = wt + (size_t)mat * 1024 * 1024;
    int tx = threadIdx.x, ty = threadIdx.y;
    if (mat == 0 || mat == 3) {
        int col = blockIdx.x * 32 + tx, row0 = blockIdx.y * 32;
#pragma unroll
        for (int j = 0; j < 32; j += 8)
            dst[(size_t)(row0 + ty + j) * 1024 + col] = f2bf(src[(size_t)(row0 + ty + j) * 1024 + col]);
    } else {
        __shared__ float tile[32][33];
        int col = blockIdx.x * 32 + tx, row0 = blockIdx.y * 32;
#pragma unroll
        for (int j = 0; j < 32; j += 8)
            tile[ty + j][tx] = src[(size_t)(row0 + ty + j) * 1024 + col];
        __syncthreads();
        int col2 = blockIdx.y * 32 + tx, row20 = blockIdx.x * 32;
#pragma unroll
        for (int j = 0; j < 32; j += 8)
            dst[(size_t)(row20 + ty + j) * 1024 + col2] = f2bf(tile[tx][ty + j]);
    }
}

// ============ deep-pipelined 128x256 bf16 GEMM (BK=64, dbuf, counted vmcnt) ============
// C = A @ Bt^T.  A: [M, lda] bf16.  Bt: [N, K] bf16.
// EPI: 0 = fp32 out, 2 = bf16 out, 3 = bf16 bias+relu out.
// bstride: if nonzero, Bt is batched per 2048 A-rows (Bt_eff = Bt + (m0>>11)*bstride).
// LDS swizzle (T2): element (row, kseg8) at byte row*128 + ((kseg^(row&7))<<4);
// global_load_lds dest linear, XOR applied to per-lane GLOBAL source (rule #21).
template <int EPI>
__global__ __launch_bounds__(512) void gemm8p(const u16* __restrict__ A,
                                              const u16* __restrict__ Bt,
                                              void* __restrict__ Cv,
                                              const float* __restrict__ bias,
                                              int N, int K, int lda, size_t bstride) {
    __shared__ __align__(16) u16 lds[49152];   // 96 KB = 2 x 24576 u16
    const int t = threadIdx.x;
    const int ntn = N >> 8;
    const int nwg = gridDim.x;                 // must be % 8 == 0 (bijective XCD swizzle)
    int bid = (int)blockIdx.x;
    bid = (bid & 7) * (nwg >> 3) + (bid >> 3);
    const int tm = bid / ntn, tn = bid - tm * ntn;
    const size_t m0 = (size_t)tm << 7, n0 = (size_t)tn << 8;
    const int w = t >> 6, lane = t & 63;
    const int wr = w >> 2, wc = w & 3;         // 2 (M) x 4 (N) waves
    const u16* Bt_e = Bt + (bstride ? (m0 >> 11) * bstride : 0);

    const int r0 = t >> 3;                      // staging row 0..63
    const int ksrc = (t & 7) ^ (r0 & 7);
    const u16* sA0 = A + (m0 + r0) * (size_t)lda + ksrc * 8;
    const u16* sA1 = sA0 + (size_t)64 * lda;
    const u16* sB0 = Bt_e + (n0 + r0) * (size_t)K + ksrc * 8;
    const u16* sB1 = sB0 + (size_t)64 * K;
    const u16* sB2 = sB0 + (size_t)128 * K;
    const u16* sB3 = sB0 + (size_t)192 * K;
    u16* dstW = lds + (w << 9);                 // wave-uniform; HW adds lane*16B

    const int ao = ((wr << 6) | (lane & 15)) << 6;            // A row * 64
    const int bo = 8192 + ((((wc << 6) | (lane & 15))) << 6); // B region + n-row * 64
    const int kx = lane & 7;
    const int ks0 = (((lane >> 4) ^ kx) << 3);
    const int ks1 = (((4 + (lane >> 4)) ^ kx) << 3);

    f32x4 acc[4][4];
#pragma unroll
    for (int i = 0; i < 4; i++)
#pragma unroll
        for (int j = 0; j < 4; j++)
#pragma unroll
            for (int r = 0; r < 4; r++) acc[i][j][r] = 0.0f;

    const int NT = K >> 6;
    lds16(sA0, dstW);          lds16(sA1, dstW + 4096);
    lds16(sB0, dstW + 8192);   lds16(sB1, dstW + 12288);
    lds16(sB2, dstW + 16384);  lds16(sB3, dstW + 20480);

    for (int kt = 0; kt < NT; kt++) {
        const int b = kt & 1;
        asm volatile("" ::: "memory");
        if (kt + 1 < NT) {
            const size_t ko = (size_t)(kt + 1) << 6;
            u16* d = dstW + (b ^ 1) * 24576;
            lds16(sA0 + ko, d);          lds16(sA1 + ko, d + 4096);
            lds16(sB0 + ko, d + 8192);   lds16(sB1 + ko, d + 12288);
            lds16(sB2 + ko, d + 16384);  lds16(sB3 + ko, d + 20480);
            asm volatile("s_waitcnt vmcnt(6)" ::: "memory");  // own kt loads retired; prefetch in flight
        } else {
            asm volatile("s_waitcnt vmcnt(0)" ::: "memory");
        }
        __builtin_amdgcn_s_barrier();
        asm volatile("" ::: "memory");
        const u16* Lb = lds + b * 24576;
#pragma unroll
        for (int kc = 0; kc < 2; kc++) {
            const int ksl = kc ? ks1 : ks0;
            bf16x8 af[4], bfr[4];
#pragma unroll
            for (int i = 0; i < 4; i++)
                af[i] = *reinterpret_cast<const bf16x8*>(Lb + ao + i * 1024 + ksl);
#pragma unroll
            for (int j = 0; j < 4; j++)
                bfr[j] = *reinterpret_cast<const bf16x8*>(Lb + bo + j * 1024 + ksl);
            __builtin_amdgcn_s_setprio(1);
#pragma unroll
            for (int i = 0; i < 4; i++)
#pragma unroll
                for (int j = 0; j < 4; j++)
                    acc[i][j] = __builtin_amdgcn_mfma_f32_16x16x32_bf16(af[i], bfr[j], acc[i][j], 0, 0, 0);
            __builtin_amdgcn_s_setprio(0);
        }
        asm volatile("" ::: "memory");
        __builtin_amdgcn_s_barrier();
    }

    const int crow = (lane >> 4) << 2, ccol = lane & 15;
#pragma unroll
    for (int i = 0; i < 4; i++)
#pragma unroll
        for (int j = 0; j < 4; j++) {
            size_t row = m0 + (wr << 6) + (i << 4) + crow;
            size_t col = n0 + (wc << 6) + (j << 4) + ccol;
#pragma unroll
            for (int r = 0; r < 4; r++) {
                float v = acc[i][j][r];
                if (EPI == 3) { v += bias[col]; v = fmaxf(v, 0.0f); }
                if (EPI == 0) ((float*)Cv)[(row + r) * (size_t)N + col] = v;
                else          ((u16*)Cv)[(row + r) * (size_t)N + col] = f2bf(v);
            }
        }
}

// ===== KtV partials: per (bh, split of 128 rows), 64x64 fp32 outer-product accumulate =====
// kv layout: [8192][2048] bf16, cols 0..1023 = K, 1024..2047 = V.
__global__ __launch_bounds__(256) void ktv_kernel(const u16* __restrict__ kv,
                                                  float* __restrict__ part) {
    const int bh = blockIdx.x, split = blockIdx.y;
    const int b = bh >> 4, h = bh & 15;
    const u16* Kp = kv + (size_t)b * 2048 * 2048 + h * 64;
    const u16* Vp = Kp + 1024;
    __shared__ float ks[8][64], vs[8][64];
    float acc[16];
#pragma unroll
    for (int i = 0; i < 16; i++) acc[i] = 0.0f;
    const int t = threadIdx.x, r = t >> 4, c = t & 15;
    const int lr = t >> 5, lc = (t & 31) * 2;
    for (int l0 = split * 128; l0 < split * 128 + 128; l0 += 8) {
        unsigned kk = *(const unsigned*)(Kp + (size_t)(l0 + lr) * 2048 + lc);
        unsigned vv = *(const unsigned*)(Vp + (size_t)(l0 + lr) * 2048 + lc);
        ks[lr][lc] = bf2f((u16)kk); ks[lr][lc + 1] = bf2f((u16)(kk >> 16));
        vs[lr][lc] = bf2f((u16)vv); vs[lr][lc + 1] = bf2f((u16)(vv >> 16));
        __syncthreads();
#pragma unroll
        for (int i = 0; i < 8; i++) {
            float kvr[4], vw[4];
#pragma unroll
            for (int a = 0; a < 4; a++) { kvr[a] = ks[i][r + 16 * a]; vw[a] = vs[i][c + 16 * a]; }
#pragma unroll
            for (int a = 0; a < 4; a++)
#pragma unroll
                for (int q = 0; q < 4; q++) acc[a * 4 + q] += kvr[a] * vw[q];
        }
        __syncthreads();
    }
    float* o = part + ((size_t)split * 64 + bh) * 4096;
#pragma unroll
    for (int a = 0; a < 4; a++)
#pragma unroll
        for (int q = 0; q < 4; q++) o[(r + 16 * a) * 64 + (c + 16 * q)] = acc[a * 4 + q];
}

__global__ __launch_bounds__(256) void ktv_reduce(const float* __restrict__ part,
                                                  float* __restrict__ ktv) {
    int i = blockIdx.x * 256 + threadIdx.x;  // 64*4096 = 262144
    float s = 0.0f;
#pragma unroll
    for (int sp = 0; sp < 16; sp++) s += part[(size_t)sp * 262144 + i];
    ktv[i] = s;
}

// ===== W'^T_b[n][h*64+i] = sum_j (KtV_bh[i][j]/8) * Wo[h*64+j][n]  -> bf16 =====
__global__ __launch_bounds__(256) void wprime_kernel(const float* __restrict__ ktv,
                                                     const float* __restrict__ Wo,
                                                     u16* __restrict__ wp) {
    const int n = blockIdx.x * 256 + threadIdx.x;   // blockIdx.x in [0,4)
    const int h = blockIdx.y, b = blockIdx.z;
    const float* kt = ktv + ((size_t)(b * 16 + h) << 12);
    float acc[64];
#pragma unroll
    for (int i = 0; i < 64; i++) acc[i] = 0.0f;
    for (int j = 0; j < 64; j++) {
        float w = Wo[(size_t)(h * 64 + j) * 1024 + n];
#pragma unroll
        for (int i = 0; i < 64; i++) acc[i] += kt[i * 64 + j] * w;
    }
    u16* o = wp + ((size_t)b << 20) + (size_t)n * 1024 + h * 64;
    u16 ob[64];
#pragma unroll
    for (int i = 0; i < 64; i++) ob[i] = f2bf(acc[i] * 0.125f);
#pragma unroll
    for (int i = 0; i < 8; i++)
        ((uint4*)o)[i] = ((const uint4*)ob)[i];
}

// ===== LN1: h = LN(seq + pos + attn_bf16); writes f32 + bf16 =====
__global__ __launch_bounds__(256) void ln_pos(const float* __restrict__ seq,
                                              const u16* __restrict__ attn,
                                              const float* __restrict__ g,
                                              const float* __restrict__ be,
                                              float* __restrict__ outF,
                                              u16* __restrict__ outB) {
    __shared__ float sm[4];
    const int row = blockIdx.x, t = threadIdx.x;
    const int l = row & 2047, e4 = t * 4;
    const float4 a = ((const float4*)(seq + (size_t)row * 1024))[t];
    const ushort4 ab = ((const ushort4*)(attn + (size_t)row * 1024))[t];
    float x0 = a.x + pos_term(l, e4 + 0) + bf2f(ab.x);
    float x1 = a.y + pos_term(l, e4 + 1) + bf2f(ab.y);
    float x2 = a.z + pos_term(l, e4 + 2) + bf2f(ab.z);
    float x3 = a.w + pos_term(l, e4 + 3) + bf2f(ab.w);
    float s = x0 + x1 + x2 + x3;
#pragma unroll
    for (int off = 32; off > 0; off >>= 1) s += __shfl_down(s, off);
    if ((t & 63) == 0) sm[t >> 6] = s;
    __syncthreads();
    const float mean = (sm[0] + sm[1] + sm[2] + sm[3]) * (1.0f / 1024.0f);
    __syncthreads();
    x0 -= mean; x1 -= mean; x2 -= mean; x3 -= mean;
    float s2 = x0 * x0 + x1 * x1 + x2 * x2 + x3 * x3;
#pragma unroll
    for (int off = 32; off > 0; off >>= 1) s2 += __shfl_down(s2, off);
    if ((t & 63) == 0) sm[t >> 6] = s2;
    __syncthreads();
    const float var = (sm[0] + sm[1] + sm[2] + sm[3]) * (1.0f / 1024.0f);
    const float rs = rsqrtf(var + 1e-5f);
    const float4 gv = ((const float4*)g)[t];
    const float4 bv = ((const float4*)be)[t];
    float y0 = x0 * rs * gv.x + bv.x;
    float y1 = x1 * rs * gv.y + bv.y;
    float y2 = x2 * rs * gv.z + bv.z;
    float y3 = x3 * rs * gv.w + bv.w;
    float4 o; o.x = y0; o.y = y1; o.z = y2; o.w = y3;
    ((float4*)(outF + (size_t)row * 1024))[t] = o;
    ushort4 ob; ob.x = f2bf(y0); ob.y = f2bf(y1); ob.z = f2bf(y2); ob.w = f2bf(y3);
    ((ushort4*)(outB + (size_t)row * 1024))[t] = ob;
}

// ===== LN2: out = LN(ff_bf16 + h1_f32); writes f32 =====
__global__ __launch_bounds__(256) void ln2_kernel(const u16* __restrict__ ff,
                                                  const float* __restrict__ h1,
                                                  const float* __restrict__ g,
                                                  const float* __restrict__ be,
                                                  float* __restrict__ outF) {
    __shared__ float sm[4];
    const int row = blockIdx.x, t = threadIdx.x;
    const ushort4 fb = ((const ushort4*)(ff + (size_t)row * 1024))[t];
    const float4 b = ((const float4*)(h1 + (size_t)row * 1024))[t];
    float x0 = bf2f(fb.x) + b.x, x1 = bf2f(fb.y) + b.y;
    float x2 = bf2f(fb.z) + b.z, x3 = bf2f(fb.w) + b.w;
    float s = x0 + x1 + x2 + x3;
#pragma unroll
    for (int off = 32; off > 0; off >>= 1) s += __shfl_down(s, off);
    if ((t & 63) == 0) sm[t >> 6] = s;
    __syncthreads();
    const float mean = (sm[0] + sm[1] + sm[2] + sm[3]) * (1.0f / 1024.0f);
    __syncthreads();
    x0 -= mean; x1 -= mean; x2 -= mean; x3 -= mean;
    float s2 = x0 * x0 + x1 * x1 + x2 * x2 + x3 * x3;
#pragma unroll
    for (int off = 32; off > 0; off >>= 1) s2 += __shfl_down(s2, off);
    if ((t & 63) == 0) sm[t >> 6] = s2;
    __syncthreads();
    const float var = (sm[0] + sm[1] + sm[2] + sm[3]) * (1.0f / 1024.0f);
    const float rs = rsqrtf(var + 1e-5f);
    const float4 gv = ((const float4*)g)[t];
    const float4 bv = ((const float4*)be)[t];
    float4 o;
    o.x = x0 * rs * gv.x + bv.x;
    o.y = x1 * rs * gv.y + bv.y;
    o.z = x2 * rs * gv.z + bv.z;
    o.w = x3 * rs * gv.w + bv.w;
    ((float4*)(outF + (size_t)row * 1024))[t] = o;
}

extern "C" void kernel_launch(void* const* d_in, const int* in_sizes, int n_in,
                              void* d_out, int out_size, void* d_ws, size_t ws_size,
                              hipStream_t stream) {
    const float* seq = (const float*)d_in[0];
    const float* Wq  = (const float*)d_in[1];
    const float* Wk  = (const float*)d_in[2];
    const float* Wv  = (const float*)d_in[3];
    const float* Wo  = (const float*)d_in[4];
    const float* g1  = (const float*)d_in[5];
    const float* b1  = (const float*)d_in[6];
    const float* Wl  = (const float*)d_in[7];
    const float* bl  = (const float*)d_in[8];
    const float* g2  = (const float*)d_in[9];
    const float* b2  = (const float*)d_in[10];

    char* ws = (char*)d_ws;
    const size_t MB = 1024 * 1024;
    u16*   x_bf  = (u16*)(ws + 0);              // 16 MB [8192][1024]
    u16*   wt    = (u16*)(ws + 16 * MB);        // 8 MB: [Wq, Wk^T, Wv^T, Wl] bf16
    u16*   kv    = (u16*)(ws + 24 * MB);        // 32 MB [8192][2048] (dead after ktv)
    float* h1f   = (float*)(ws + 24 * MB);      // 32 MB (reuses kv)
    float* kpart = (float*)(ws + 56 * MB);      // 16 MB [16][64][4096] (dead after reduce)
    u16*   attn  = (u16*)(ws + 56 * MB);        // 16 MB (reuses kpart)
    float* ktv   = (float*)(ws + 72 * MB);      // 1 MB  [64][64][64]
    u16*   wpr   = (u16*)(ws + 73 * MB);        // 8 MB  [4][1024][1024] W'^T per batch
    u16*   wcomb = (u16*)(ws + 81 * MB);        // 8 MB  [4][1024][1024] Wcomb^T per batch
    u16*   h1b   = (u16*)(ws + 89 * MB);        // 16 MB
    u16*   ffb   = (u16*)(ws + 105 * MB);       // 16 MB

    // 1. x_bf = bf16(seq + positional)
    prep_x<<<dim3(8192), dim3(256), 0, stream>>>(seq, x_bf);
    // 2. weights -> bf16
    prep_w<<<dim3(32, 32, 4), dim3(32, 8), 0, stream>>>(Wq, Wk, Wv, Wl, wt);
    // 3. kv = x @ [Wk|Wv]: [8192,1024]@[1024,2048] -> bf16  (grid 64x8 = 512)
    gemm8p<2><<<dim3(512), dim3(512), 0, stream>>>(x_bf, wt + (size_t)1 * MB, kv, nullptr,
                                                   2048, 1024, 1024, 0);
    // 4. KtV per (b,h), deterministic two-stage
    ktv_kernel<<<dim3(64, 16), dim3(256), 0, stream>>>(kv, kpart);
    ktv_reduce<<<dim3(1024), dim3(256), 0, stream>>>(kpart, ktv);
    // 5. W'^T_b = (blockdiag(KtV_b)/8 @ W_o)^T -> bf16
    wprime_kernel<<<dim3(4, 16, 4), dim3(256), 0, stream>>>(ktv, Wo, wpr);
    // 6. Wcomb^T_b = W'^T_b @ Wq(direct): [4096,1024]@... (grid 32x4 = 128)
    gemm8p<2><<<dim3(128), dim3(512), 0, stream>>>(wpr, wt, wcomb, nullptr,
                                                   1024, 1024, 1024, 0);
    // 7. attn = x @ Wcomb_b -> bf16  (B batched per 2048 rows; grid 64x4 = 256)
    gemm8p<2><<<dim3(256), dim3(512), 0, stream>>>(x_bf, wcomb, attn, nullptr,
                                                   1024, 1024, 1024, (size_t)1024 * 1024);
    // 8. h1 = LN(seq + pos + attn)  (recomputes pos inline)
    ln_pos<<<dim3(8192), dim3(256), 0, stream>>>(seq, attn, g1, b1, h1f, h1b);
    // 9. ff = relu(h1 @ Wl^T + bl) -> bf16  (grid 256)
    gemm8p<3><<<dim3(256), dim3(512), 0, stream>>>(h1b, wt + (size_t)3 * MB, ffb,
                                                   bl, 1024, 1024, 1024, 0);
    // 10. out = LN(ff + h1)
    ln2_kernel<<<dim3(8192), dim3(256), 0, stream>>>(ffb, h1f, g2, b2, (float*)d_out);
}

// Round 5
// 201.821 us; speedup vs baseline: 1.5514x; 1.0532x over previous
//
#include <hip/hip_runtime.h>
#include <cstdint>

typedef unsigned short u16;
typedef __bf16 bf16x8 __attribute__((ext_vector_type(8)));
typedef float f32x4 __attribute__((ext_vector_type(4)));

// ---------- bf16 helpers (RNE) ----------
__device__ __forceinline__ u16 f2bf(float f) {
    unsigned u = __float_as_uint(f);
    u += 0x7fffu + ((u >> 16) & 1u);
    return (u16)(u >> 16);
}
__device__ __forceinline__ float bf2f(u16 h) {
    return __uint_as_float(((unsigned)h) << 16);
}

// ---------- async global->LDS (16B per lane, wave-uniform LDS base) ----------
__device__ __forceinline__ void lds16(const void* g, void* l) {
    __builtin_amdgcn_global_load_lds(
        (const __attribute__((address_space(1))) void*)g,
        (__attribute__((address_space(3))) void*)l, 16, 0, 0);
}

// ---------- positional encoding term for element e of row l ----------
__device__ __forceinline__ float pos_term(int l, int e) {
    const float c = -13.287712379549449f / 512.0f;       // -log2(10000)/512
    int ii = e & 511;
    float st  = exp2f(c * (float)ii);
    float arg = (float)l * st;
    return (e < 512) ? sinf(arg) : cosf(arg);
}

// ================= prep: x_bf = bf16(seq + positional) =================
__global__ __launch_bounds__(256) void prep_x(const float* __restrict__ seq,
                                              u16* __restrict__ xb) {
    size_t i = (size_t)blockIdx.x * 256 + threadIdx.x;   // float4 index, 2M total
    int e4 = (int)(i & 255) * 4;
    int l  = (int)((i >> 8) & 2047);
    float4 s = ((const float4*)seq)[i];
    float v[4] = {s.x, s.y, s.z, s.w};
#pragma unroll
    for (int j = 0; j < 4; j++) v[j] += pos_term(l, e4 + j);
    ushort4 ob; ob.x = f2bf(v[0]); ob.y = f2bf(v[1]); ob.z = f2bf(v[2]); ob.w = f2bf(v[3]);
    ((ushort4*)xb)[i] = ob;
}

// ===== weights -> bf16: mat0 = Wq direct, mat1 = Wk^T, mat2 = Wv^T, mat3 = Wl direct =====
__global__ void prep_w(const float* __restrict__ wq, const float* __restrict__ wk,
                       const float* __restrict__ wv, const float* __restrict__ wl,
                       u16* __restrict__ wt) {
    int mat = blockIdx.z;
    const float* src = (mat == 0) ? wq : (mat == 1) ? wk : (mat == 2) ? wv : wl;
    u16* dst = wt + (size_t)mat * 1024 * 1024;
    int tx = threadIdx.x, ty = threadIdx.y;
    if (mat == 0 || mat == 3) {
        int col = blockIdx.x * 32 + tx, row0 = blockIdx.y * 32;
#pragma unroll
        for (int j = 0; j < 32; j += 8)
            dst[(size_t)(row0 + ty + j) * 1024 + col] = f2bf(src[(size_t)(row0 + ty + j) * 1024 + col]);
    } else {
        __shared__ float tile[32][33];
        int col = blockIdx.x * 32 + tx, row0 = blockIdx.y * 32;
#pragma unroll
        for (int j = 0; j < 32; j += 8)
            tile[ty + j][tx] = src[(size_t)(row0 + ty + j) * 1024 + col];
        __syncthreads();
        int col2 = blockIdx.y * 32 + tx, row20 = blockIdx.x * 32;
#pragma unroll
        for (int j = 0; j < 32; j += 8)
            dst[(size_t)(row20 + ty + j) * 1024 + col2] = f2bf(tile[tx][ty + j]);
    }
}

// ======== 256x256 8-phase bf16 GEMM (BK=64, dbuf, counted vmcnt, T2+T3+T4+T5) ========
// C = A @ Bt^T -> bf16.  A: [M, lda] bf16.  Bt: [N, K] bf16.  Grid must be %8==0.
// 512 threads = 8 waves (2M x 4N); per-wave output 128x64 = acc[8][4] f32x4.
// LDS 128 KB: dbuf b at u16 offset b*32768; A rows 0..255 at row*64, B at +16384.
// Swizzle (T2, measured conflict-free in R3/R4): element (row, kseg8) stored at
// kslot = kseg ^ (row&7); gload_lds dest linear, XOR applied to global source.
// Per K-tile: 4 phases (mq,nq quadrants); per phase: ds_read subtile (pre-barrier),
// stage 1-2 half-tiles of tile t+1, [vmcnt(4) at phase 0 only], barrier,
// setprio(1) 16 MFMA setprio(0), barrier.
// vmcnt proof (per-thread queue): prologue stages tile0 (8 loads). Iter t phase0
// issues tile(t+1) h0,h1 (4 loads) -> queue=[tile_t:8, tile_t+1:4]; vmcnt(4)
// retires tile_t's 8; barrier makes that true for ALL waves before any ds_read
// of tile t. Phases 1,2 add h2,h3. Last iter: vmcnt(0). Overwrite of dbuf[b^1]
// (tile t-1) is safe: every wave's tile t-1 ds_reads completed before its final
// barrier of iter t-1 (lgkm waits precede MFMA which precedes the barrier).
__global__ __launch_bounds__(512) void gemm256(const u16* __restrict__ A,
                                               const u16* __restrict__ Bt,
                                               u16* __restrict__ C,
                                               int N, int K, int lda) {
    __shared__ __align__(16) u16 lds[65536];   // 128 KB
    const int t = threadIdx.x;
    const int ntn = N >> 8;
    const int nwg = gridDim.x;
    int bid = (int)blockIdx.x;
    bid = (bid & 7) * (nwg >> 3) + (bid >> 3);        // bijective XCD swizzle (nwg%8==0)
    const int tm = bid / ntn, tn = bid - tm * ntn;
    const size_t m0 = (size_t)tm << 8, n0 = (size_t)tn << 8;
    const int w = t >> 6, lane = t & 63;
    const int wr = w >> 2, wc = w & 3;                // 2 (M) x 4 (N)

    // staging sources: thread covers rows r0 and r0+64 of each 128-row half-tile
    const int r0 = t >> 3;
    const int ksrc = (t & 7) ^ (r0 & 7);              // inverse swizzle on global source
    const u16* sA0 = A + (m0 + r0) * (size_t)lda + ksrc * 8;   // A rows 0..127
    const u16* sA1 = sA0 + (size_t)128 * lda;                  // A rows 128..255
    const u16* sB0 = Bt + (n0 + r0) * (size_t)K + ksrc * 8;    // B rows 0..127
    const u16* sB1 = sB0 + (size_t)128 * K;                    // B rows 128..255
    const size_t stA = (size_t)64 * lda, stB = (size_t)64 * K;

#define STAGE(bb, hh, src, str, ko)                                           \
    do {                                                                      \
        u16* d_ = lds + (bb) * 32768 + (hh) * 8192 + (w << 9);                \
        lds16((src) + (ko), d_);                                              \
        lds16((src) + (ko) + (str), d_ + 4096);                               \
    } while (0)

    // fragment read offsets
    const int kx = lane & 7;
    const int ks0 = (((lane >> 4) ^ kx) << 3);        // kc=0
    const int ks1 = (((4 + (lane >> 4)) ^ kx) << 3);  // kc=1
    const int arow = (wr << 7) + (lane & 15);         // + mq*64 + i*16
    const int brow = (wc << 6) + (lane & 15);         // + nq*32 + j*16

    f32x4 acc[8][4];
#pragma unroll
    for (int i = 0; i < 8; i++)
#pragma unroll
        for (int j = 0; j < 4; j++)
#pragma unroll
            for (int r = 0; r < 4; r++) acc[i][j][r] = 0.0f;

    const int NT = K >> 6;
    // prologue: stage tile 0 into dbuf 0
    STAGE(0, 0, sA0, stA, 0); STAGE(0, 1, sA1, stA, 0);
    STAGE(0, 2, sB0, stB, 0); STAGE(0, 3, sB1, stB, 0);

    for (int kt = 0; kt < NT; kt++) {
        const int b = kt & 1;
        const u16* Lb = lds + b * 32768;
        const size_t ko = (size_t)(kt + 1) << 6;
        const bool pf = (kt + 1 < NT);
        bf16x8 af[4][2], bfr[2][2];
#pragma unroll
        for (int ph = 0; ph < 4; ph++) {
            const int mq = ph >> 1, nq = ph & 1;
            if (ph == 0) {
                if (pf) {
                    STAGE(b ^ 1, 0, sA0, stA, ko);
                    STAGE(b ^ 1, 1, sA1, stA, ko);
                    asm volatile("s_waitcnt vmcnt(4)" ::: "memory");
                } else {
                    asm volatile("s_waitcnt vmcnt(0)" ::: "memory");
                }
                __builtin_amdgcn_s_barrier();          // tile kt fully resident for all waves
                asm volatile("" ::: "memory");
            }
            // ds_read this phase's fragments (phases 1-3: before their barrier)
            if (ph == 0 || ph == 2) {                  // new A quadrant + B(nq=0)
#pragma unroll
                for (int i = 0; i < 4; i++) {
                    const int ar = (arow + mq * 64 + i * 16) << 6;
                    af[i][0] = *reinterpret_cast<const bf16x8*>(Lb + ar + ks0);
                    af[i][1] = *reinterpret_cast<const bf16x8*>(Lb + ar + ks1);
                }
            }
#pragma unroll
            for (int j = 0; j < 2; j++) {              // B(nq) always
                const int br = 16384 + ((brow + nq * 32 + j * 16) << 6);
                bfr[j][0] = *reinterpret_cast<const bf16x8*>(Lb + br + ks0);
                bfr[j][1] = *reinterpret_cast<const bf16x8*>(Lb + br + ks1);
            }
            if (ph == 1 && pf) STAGE(b ^ 1, 2, sB0, stB, ko);
            if (ph == 2 && pf) STAGE(b ^ 1, 3, sB1, stB, ko);
            asm volatile("" ::: "memory");
            if (ph != 0) __builtin_amdgcn_s_barrier(); // phase rendezvous (pre-MFMA)
            __builtin_amdgcn_s_setprio(1);
#pragma unroll
            for (int kc = 0; kc < 2; kc++)
#pragma unroll
                for (int i = 0; i < 4; i++)
#pragma unroll
                    for (int j = 0; j < 2; j++)
                        acc[mq * 4 + i][nq * 2 + j] = __builtin_amdgcn_mfma_f32_16x16x32_bf16(
                            af[i][kc], bfr[j][kc], acc[mq * 4 + i][nq * 2 + j], 0, 0, 0);
            __builtin_amdgcn_s_setprio(0);
            asm volatile("" ::: "memory");
            __builtin_amdgcn_s_barrier();              // post-MFMA rendezvous
        }
    }
#undef STAGE

    // epilogue: bf16 store
    const int crow = (lane >> 4) << 2, ccol = lane & 15;
#pragma unroll
    for (int i = 0; i < 8; i++)
#pragma unroll
        for (int j = 0; j < 4; j++) {
            size_t row = m0 + (wr << 7) + (i << 4) + crow;
            size_t col = n0 + (wc << 6) + (j << 4) + ccol;
#pragma unroll
            for (int r = 0; r < 4; r++)
                C[(row + r) * (size_t)N + col] = f2bf(acc[i][j][r]);
        }
}

// ============ 128x256 bf16 GEMM (BK=64, dbuf, counted vmcnt) — small/odd grids ============
// EPI: 2 = bf16 out, 3 = bf16 bias+relu out.
// bstride: if nonzero, Bt is batched per 2048 A-rows (Bt_eff = Bt + (m0>>11)*bstride).
template <int EPI>
__global__ __launch_bounds__(512) void gemm8p(const u16* __restrict__ A,
                                              const u16* __restrict__ Bt,
                                              void* __restrict__ Cv,
                                              const float* __restrict__ bias,
                                              int N, int K, int lda, size_t bstride) {
    __shared__ __align__(16) u16 lds[49152];   // 96 KB = 2 x 24576 u16
    const int t = threadIdx.x;
    const int ntn = N >> 8;
    const int nwg = gridDim.x;                 // must be % 8 == 0
    int bid = (int)blockIdx.x;
    bid = (bid & 7) * (nwg >> 3) + (bid >> 3);
    const int tm = bid / ntn, tn = bid - tm * ntn;
    const size_t m0 = (size_t)tm << 7, n0 = (size_t)tn << 8;
    const int w = t >> 6, lane = t & 63;
    const int wr = w >> 2, wc = w & 3;         // 2 (M) x 4 (N) waves
    const u16* Bt_e = Bt + (bstride ? (m0 >> 11) * bstride : 0);

    const int r0 = t >> 3;
    const int ksrc = (t & 7) ^ (r0 & 7);
    const u16* sA0 = A + (m0 + r0) * (size_t)lda + ksrc * 8;
    const u16* sA1 = sA0 + (size_t)64 * lda;
    const u16* sB0 = Bt_e + (n0 + r0) * (size_t)K + ksrc * 8;
    const u16* sB1 = sB0 + (size_t)64 * K;
    const u16* sB2 = sB0 + (size_t)128 * K;
    const u16* sB3 = sB0 + (size_t)192 * K;
    u16* dstW = lds + (w << 9);

    const int ao = ((wr << 6) | (lane & 15)) << 6;
    const int bo = 8192 + ((((wc << 6) | (lane & 15))) << 6);
    const int kx = lane & 7;
    const int ks0 = (((lane >> 4) ^ kx) << 3);
    const int ks1 = (((4 + (lane >> 4)) ^ kx) << 3);

    f32x4 acc[4][4];
#pragma unroll
    for (int i = 0; i < 4; i++)
#pragma unroll
        for (int j = 0; j < 4; j++)
#pragma unroll
            for (int r = 0; r < 4; r++) acc[i][j][r] = 0.0f;

    const int NT = K >> 6;
    lds16(sA0, dstW);          lds16(sA1, dstW + 4096);
    lds16(sB0, dstW + 8192);   lds16(sB1, dstW + 12288);
    lds16(sB2, dstW + 16384);  lds16(sB3, dstW + 20480);

    for (int kt = 0; kt < NT; kt++) {
        const int b = kt & 1;
        asm volatile("" ::: "memory");
        if (kt + 1 < NT) {
            const size_t ko = (size_t)(kt + 1) << 6;
            u16* d = dstW + (b ^ 1) * 24576;
            lds16(sA0 + ko, d);          lds16(sA1 + ko, d + 4096);
            lds16(sB0 + ko, d + 8192);   lds16(sB1 + ko, d + 12288);
            lds16(sB2 + ko, d + 16384);  lds16(sB3 + ko, d + 20480);
            asm volatile("s_waitcnt vmcnt(6)" ::: "memory");
        } else {
            asm volatile("s_waitcnt vmcnt(0)" ::: "memory");
        }
        __builtin_amdgcn_s_barrier();
        asm volatile("" ::: "memory");
        const u16* Lb = lds + b * 24576;
#pragma unroll
        for (int kc = 0; kc < 2; kc++) {
            const int ksl = kc ? ks1 : ks0;
            bf16x8 af[4], bfr[4];
#pragma unroll
            for (int i = 0; i < 4; i++)
                af[i] = *reinterpret_cast<const bf16x8*>(Lb + ao + i * 1024 + ksl);
#pragma unroll
            for (int j = 0; j < 4; j++)
                bfr[j] = *reinterpret_cast<const bf16x8*>(Lb + bo + j * 1024 + ksl);
            __builtin_amdgcn_s_setprio(1);
#pragma unroll
            for (int i = 0; i < 4; i++)
#pragma unroll
                for (int j = 0; j < 4; j++)
                    acc[i][j] = __builtin_amdgcn_mfma_f32_16x16x32_bf16(af[i], bfr[j], acc[i][j], 0, 0, 0);
            __builtin_amdgcn_s_setprio(0);
        }
        asm volatile("" ::: "memory");
        __builtin_amdgcn_s_barrier();
    }

    const int crow = (lane >> 4) << 2, ccol = lane & 15;
#pragma unroll
    for (int i = 0; i < 4; i++)
#pragma unroll
        for (int j = 0; j < 4; j++) {
            size_t row = m0 + (wr << 6) + (i << 4) + crow;
            size_t col = n0 + (wc << 6) + (j << 4) + ccol;
#pragma unroll
            for (int r = 0; r < 4; r++) {
                float v = acc[i][j][r];
                if (EPI == 3) { v += bias[col]; v = fmaxf(v, 0.0f); }
                ((u16*)Cv)[(row + r) * (size_t)N + col] = f2bf(v);
            }
        }
}

// ===== KtV partials: per (bh, split of 128 rows), 64x64 fp32 outer-product accumulate =====
// kv layout: [8192][2048] bf16, cols 0..1023 = K, 1024..2047 = V.
__global__ __launch_bounds__(256) void ktv_kernel(const u16* __restrict__ kv,
                                                  float* __restrict__ part) {
    const int bh = blockIdx.x, split = blockIdx.y;
    const int b = bh >> 4, h = bh & 15;
    const u16* Kp = kv + (size_t)b * 2048 * 2048 + h * 64;
    const u16* Vp = Kp + 1024;
    __shared__ float ks[8][64], vs[8][64];
    float acc[16];
#pragma unroll
    for (int i = 0; i < 16; i++) acc[i] = 0.0f;
    const int t = threadIdx.x, r = t >> 4, c = t & 15;
    const int lr = t >> 5, lc = (t & 31) * 2;
    for (int l0 = split * 128; l0 < split * 128 + 128; l0 += 8) {
        unsigned kk = *(const unsigned*)(Kp + (size_t)(l0 + lr) * 2048 + lc);
        unsigned vv = *(const unsigned*)(Vp + (size_t)(l0 + lr) * 2048 + lc);
        ks[lr][lc] = bf2f((u16)kk); ks[lr][lc + 1] = bf2f((u16)(kk >> 16));
        vs[lr][lc] = bf2f((u16)vv); vs[lr][lc + 1] = bf2f((u16)(vv >> 16));
        __syncthreads();
#pragma unroll
        for (int i = 0; i < 8; i++) {
            float kvr[4], vw[4];
#pragma unroll
            for (int a = 0; a < 4; a++) { kvr[a] = ks[i][r + 16 * a]; vw[a] = vs[i][c + 16 * a]; }
#pragma unroll
            for (int a = 0; a < 4; a++)
#pragma unroll
                for (int q = 0; q < 4; q++) acc[a * 4 + q] += kvr[a] * vw[q];
        }
        __syncthreads();
    }
    float* o = part + ((size_t)split * 64 + bh) * 4096;
#pragma unroll
    for (int a = 0; a < 4; a++)
#pragma unroll
        for (int q = 0; q < 4; q++) o[(r + 16 * a) * 64 + (c + 16 * q)] = acc[a * 4 + q];
}

__global__ __launch_bounds__(256) void ktv_reduce(const float* __restrict__ part,
                                                  float* __restrict__ ktv) {
    int i = blockIdx.x * 256 + threadIdx.x;  // 64*4096 = 262144
    float s = 0.0f;
#pragma unroll
    for (int sp = 0; sp < 16; sp++) s += part[(size_t)sp * 262144 + i];
    ktv[i] = s;
}

// ===== W'^T_b[n][h*64+i] = sum_j (KtV_bh[i][j]/8) * Wo[h*64+j][n]  -> bf16 =====
__global__ __launch_bounds__(256) void wprime_kernel(const float* __restrict__ ktv,
                                                     const float* __restrict__ Wo,
                                                     u16* __restrict__ wp) {
    const int n = blockIdx.x * 256 + threadIdx.x;   // blockIdx.x in [0,4)
    const int h = blockIdx.y, b = blockIdx.z;
    const float* kt = ktv + ((size_t)(b * 16 + h) << 12);
    float acc[64];
#pragma unroll
    for (int i = 0; i < 64; i++) acc[i] = 0.0f;
    for (int j = 0; j < 64; j++) {
        float w = Wo[(size_t)(h * 64 + j) * 1024 + n];
#pragma unroll
        for (int i = 0; i < 64; i++) acc[i] += kt[i * 64 + j] * w;
    }
    u16* o = wp + ((size_t)b << 20) + (size_t)n * 1024 + h * 64;
    u16 ob[64];
#pragma unroll
    for (int i = 0; i < 64; i++) ob[i] = f2bf(acc[i] * 0.125f);
#pragma unroll
    for (int i = 0; i < 8; i++)
        ((uint4*)o)[i] = ((const uint4*)ob)[i];
}

// ===== LN1: h1b = bf16(LN(x_bf + attn_bf)) =====
__global__ __launch_bounds__(256) void ln1_kernel(const u16* __restrict__ xb,
                                                  const u16* __restrict__ attn,
                                                  const float* __restrict__ g,
                                                  const float* __restrict__ be,
                                                  u16* __restrict__ outB) {
    __shared__ float sm[4];
    const int row = blockIdx.x, t = threadIdx.x;
    const ushort4 xv = ((const ushort4*)(xb + (size_t)row * 1024))[t];
    const ushort4 av = ((const ushort4*)(attn + (size_t)row * 1024))[t];
    float x0 = bf2f(xv.x) + bf2f(av.x), x1 = bf2f(xv.y) + bf2f(av.y);
    float x2 = bf2f(xv.z) + bf2f(av.z), x3 = bf2f(xv.w) + bf2f(av.w);
    float s = x0 + x1 + x2 + x3;
#pragma unroll
    for (int off = 32; off > 0; off >>= 1) s += __shfl_down(s, off);
    if ((t & 63) == 0) sm[t >> 6] = s;
    __syncthreads();
    const float mean = (sm[0] + sm[1] + sm[2] + sm[3]) * (1.0f / 1024.0f);
    __syncthreads();
    x0 -= mean; x1 -= mean; x2 -= mean; x3 -= mean;
    float s2 = x0 * x0 + x1 * x1 + x2 * x2 + x3 * x3;
#pragma unroll
    for (int off = 32; off > 0; off >>= 1) s2 += __shfl_down(s2, off);
    if ((t & 63) == 0) sm[t >> 6] = s2;
    __syncthreads();
    const float var = (sm[0] + sm[1] + sm[2] + sm[3]) * (1.0f / 1024.0f);
    const float rs = rsqrtf(var + 1e-5f);
    const float4 gv = ((const float4*)g)[t];
    const float4 bv = ((const float4*)be)[t];
    ushort4 ob;
    ob.x = f2bf(x0 * rs * gv.x + bv.x);
    ob.y = f2bf(x1 * rs * gv.y + bv.y);
    ob.z = f2bf(x2 * rs * gv.z + bv.z);
    ob.w = f2bf(x3 * rs * gv.w + bv.w);
    ((ushort4*)(outB + (size_t)row * 1024))[t] = ob;
}

// ===== LN2: out = f32(LN(ff_bf + h1_bf)) =====
__global__ __launch_bounds__(256) void ln2_kernel(const u16* __restrict__ ff,
                                                  const u16* __restrict__ h1,
                                                  const float* __restrict__ g,
                                                  const float* __restrict__ be,
                                                  float* __restrict__ outF) {
    __shared__ float sm[4];
    const int row = blockIdx.x, t = threadIdx.x;
    const ushort4 fv = ((const ushort4*)(ff + (size_t)row * 1024))[t];
    const ushort4 hv = ((const ushort4*)(h1 + (size_t)row * 1024))[t];
    float x0 = bf2f(fv.x) + bf2f(hv.x), x1 = bf2f(fv.y) + bf2f(hv.y);
    float x2 = bf2f(fv.z) + bf2f(hv.z), x3 = bf2f(fv.w) + bf2f(hv.w);
    float s = x0 + x1 + x2 + x3;
#pragma unroll
    for (int off = 32; off > 0; off >>= 1) s += __shfl_down(s, off);
    if ((t & 63) == 0) sm[t >> 6] = s;
    __syncthreads();
    const float mean = (sm[0] + sm[1] + sm[2] + sm[3]) * (1.0f / 1024.0f);
    __syncthreads();
    x0 -= mean; x1 -= mean; x2 -= mean; x3 -= mean;
    float s2 = x0 * x0 + x1 * x1 + x2 * x2 + x3 * x3;
#pragma unroll
    for (int off = 32; off > 0; off >>= 1) s2 += __shfl_down(s2, off);
    if ((t & 63) == 0) sm[t >> 6] = s2;
    __syncthreads();
    const float var = (sm[0] + sm[1] + sm[2] + sm[3]) * (1.0f / 1024.0f);
    const float rs = rsqrtf(var + 1e-5f);
    const float4 gv = ((const float4*)g)[t];
    const float4 bv = ((const float4*)be)[t];
    float4 o;
    o.x = x0 * rs * gv.x + bv.x;
    o.y = x1 * rs * gv.y + bv.y;
    o.z = x2 * rs * gv.z + bv.z;
    o.w = x3 * rs * gv.w + bv.w;
    ((float4*)(outF + (size_t)row * 1024))[t] = o;
}

extern "C" void kernel_launch(void* const* d_in, const int* in_sizes, int n_in,
                              void* d_out, int out_size, void* d_ws, size_t ws_size,
                              hipStream_t stream) {
    const float* seq = (const float*)d_in[0];
    const float* Wq  = (const float*)d_in[1];
    const float* Wk  = (const float*)d_in[2];
    const float* Wv  = (const float*)d_in[3];
    const float* Wo  = (const float*)d_in[4];
    const float* g1  = (const float*)d_in[5];
    const float* b1  = (const float*)d_in[6];
    const float* Wl  = (const float*)d_in[7];
    const float* bl  = (const float*)d_in[8];
    const float* g2  = (const float*)d_in[9];
    const float* b2  = (const float*)d_in[10];

    char* ws = (char*)d_ws;
    const size_t MB = 1024 * 1024;
    u16*   x_bf  = (u16*)(ws + 0);              // 16 MB [8192][1024]
    u16*   wt    = (u16*)(ws + 16 * MB);        // 8 MB: [Wq, Wk^T, Wv^T, Wl] bf16
    u16*   kv    = (u16*)(ws + 24 * MB);        // 32 MB [8192][2048] (dead after ktv)
    float* kpart = (float*)(ws + 56 * MB);      // 16 MB [16][64][4096] (dead after reduce)
    u16*   attn  = (u16*)(ws + 56 * MB);        // 16 MB (reuses kpart)
    float* ktv   = (float*)(ws + 72 * MB);      // 1 MB  [64][64][64]
    u16*   wpr   = (u16*)(ws + 73 * MB);        // 8 MB  [4][1024][1024] W'^T per batch
    u16*   wcomb = (u16*)(ws + 81 * MB);        // 8 MB  [4][1024][1024] Wcomb^T per batch
    u16*   h1b   = (u16*)(ws + 89 * MB);        // 16 MB
    u16*   ffb   = (u16*)(ws + 105 * MB);       // 16 MB

    // 1. x_bf = bf16(seq + positional)
    prep_x<<<dim3(8192), dim3(256), 0, stream>>>(seq, x_bf);
    // 2. weights -> bf16
    prep_w<<<dim3(32, 32, 4), dim3(32, 8), 0, stream>>>(Wq, Wk, Wv, Wl, wt);
    // 3. kv = x @ [Wk|Wv]: [8192,1024]@[1024,2048] -> bf16  (8-phase 256^2; grid 32x8=256)
    gemm256<<<dim3(256), dim3(512), 0, stream>>>(x_bf, wt + (size_t)1 * MB, kv,
                                                 2048, 1024, 1024);
    // 4. KtV per (b,h), deterministic two-stage
    ktv_kernel<<<dim3(64, 16), dim3(256), 0, stream>>>(kv, kpart);
    ktv_reduce<<<dim3(1024), dim3(256), 0, stream>>>(kpart, ktv);
    // 5. W'^T_b = (blockdiag(KtV_b)/8 @ W_o)^T -> bf16
    wprime_kernel<<<dim3(4, 16, 4), dim3(256), 0, stream>>>(ktv, Wo, wpr);
    // 6. Wcomb^T_b = W'^T_b @ Wq: grid 32x4 = 128
    gemm8p<2><<<dim3(128), dim3(512), 0, stream>>>(wpr, wt, wcomb, nullptr,
                                                   1024, 1024, 1024, 0);
    // 7. attn = x @ Wcomb_b -> bf16  (B batched per 2048 rows; grid 64x4 = 256)
    gemm8p<2><<<dim3(256), dim3(512), 0, stream>>>(x_bf, wcomb, attn, nullptr,
                                                   1024, 1024, 1024, (size_t)1024 * 1024);
    // 8. h1b = bf16(LN(x_bf + attn))
    ln1_kernel<<<dim3(8192), dim3(256), 0, stream>>>(x_bf, attn, g1, b1, h1b);
    // 9. ff = relu(h1 @ Wl^T + bl) -> bf16  (grid 256)
    gemm8p<3><<<dim3(256), dim3(512), 0, stream>>>(h1b, wt + (size_t)3 * MB, ffb,
                                                   bl, 1024, 1024, 1024, 0);
    // 10. out = LN(ff + h1)
    ln2_kernel<<<dim3(8192), dim3(256), 0, stream>>>(ffb, h1b, g2, b2, (float*)d_out);
}

// Round 6
// 201.453 us; speedup vs baseline: 1.5542x; 1.0018x over previous
//
#include <hip/hip_runtime.h>
#include <cstdint>

typedef unsigned short u16;
typedef __bf16 bf16x8 __attribute__((ext_vector_type(8)));
typedef float f32x4 __attribute__((ext_vector_type(4)));

// ---------- bf16 helpers (RNE) ----------
__device__ __forceinline__ u16 f2bf(float f) {
    unsigned u = __float_as_uint(f);
    u += 0x7fffu + ((u >> 16) & 1u);
    return (u16)(u >> 16);
}
__device__ __forceinline__ float bf2f(u16 h) {
    return __uint_as_float(((unsigned)h) << 16);
}

// ---------- async global->LDS (16B per lane, wave-uniform LDS base) ----------
__device__ __forceinline__ void lds16(const void* g, void* l) {
    __builtin_amdgcn_global_load_lds(
        (const __attribute__((address_space(1))) void*)g,
        (__attribute__((address_space(3))) void*)l, 16, 0, 0);
}

// ---------- positional encoding term for element e of row l ----------
__device__ __forceinline__ float pos_term(int l, int e) {
    const float c = -13.287712379549449f / 512.0f;       // -log2(10000)/512
    int ii = e & 511;
    float st  = exp2f(c * (float)ii);
    float arg = (float)l * st;
    return (e < 512) ? sinf(arg) : cosf(arg);
}

// ================= prep: x_bf = bf16(seq + positional) =================
__global__ __launch_bounds__(256) void prep_x(const float* __restrict__ seq,
                                              u16* __restrict__ xb) {
    size_t i = (size_t)blockIdx.x * 256 + threadIdx.x;   // float4 index, 2M total
    int e4 = (int)(i & 255) * 4;
    int l  = (int)((i >> 8) & 2047);
    float4 s = ((const float4*)seq)[i];
    float v[4] = {s.x, s.y, s.z, s.w};
#pragma unroll
    for (int j = 0; j < 4; j++) v[j] += pos_term(l, e4 + j);
    ushort4 ob; ob.x = f2bf(v[0]); ob.y = f2bf(v[1]); ob.z = f2bf(v[2]); ob.w = f2bf(v[3]);
    ((ushort4*)xb)[i] = ob;
}

// ===== weights -> bf16: mat0 = Wq direct, mat1 = Wk^T, mat2 = Wv^T, mat3 = Wl direct =====
__global__ void prep_w(const float* __restrict__ wq, const float* __restrict__ wk,
                       const float* __restrict__ wv, const float* __restrict__ wl,
                       u16* __restrict__ wt) {
    int mat = blockIdx.z;
    const float* src = (mat == 0) ? wq : (mat == 1) ? wk : (mat == 2) ? wv : wl;
    u16* dst = wt + (size_t)mat * 1024 * 1024;
    int tx = threadIdx.x, ty = threadIdx.y;
    if (mat == 0 || mat == 3) {
        int col = blockIdx.x * 32 + tx, row0 = blockIdx.y * 32;
#pragma unroll
        for (int j = 0; j < 32; j += 8)
            dst[(size_t)(row0 + ty + j) * 1024 + col] = f2bf(src[(size_t)(row0 + ty + j) * 1024 + col]);
    } else {
        __shared__ float tile[32][33];
        int col = blockIdx.x * 32 + tx, row0 = blockIdx.y * 32;
#pragma unroll
        for (int j = 0; j < 32; j += 8)
            tile[ty + j][tx] = src[(size_t)(row0 + ty + j) * 1024 + col];
        __syncthreads();
        int col2 = blockIdx.y * 32 + tx, row20 = blockIdx.x * 32;
#pragma unroll
        for (int j = 0; j < 32; j += 8)
            dst[(size_t)(row20 + ty + j) * 1024 + col2] = f2bf(tile[tx][ty + j]);
    }
}

// ======== 256x256 8-phase bf16 GEMM — faithful m201 rhythm ========
// C = A @ Bt^T -> bf16.  512 threads = 8 waves (2M x 4N); per-wave out 128x64.
// LDS 128 KB dbuf. Swizzle: (row,kseg8) at kslot = kseg ^ (row&7); gload_lds dest
// linear, XOR on global source (rule #21). Verified conflict-free (R3-R5: 0 conflicts).
//
// Per K-tile t (buf b=t&1), 4 phases; B quads persist in regs (read once):
//  ph0: read af(mq0) 8 + B0 4 [lgkm(8)]; stage t+1.B0; BAR; lgkm0; 16 MFMA(00); BAR
//  ph1: read B1 4;                       stage t+1.B1; BAR; lgkm0; 16 MFMA(01); BAR
//  ph2: read af(mq1) 8;                                BAR; lgkm0; 16 MFMA(10); BAR
//  ph3: stage t+2.A0+A1 (into buf b: safe — all tile-t reads completed before
//       ph2's post-MFMA barrier); vmcnt(4);            BAR;        16 MFMA(11); BAR
// vmcnt proof: in-flight at ph3 wait = [t+1.A0,A1 (staged t-1.ph3), t+1.B0 (ph0),
// t+1.B1 (ph1), t+2.A0,A1 (ph3)] = 12 loads; vmcnt(4) retires all of t+1, leaves
// t+2's 4 in flight (never 0 in-loop). Prologue: t0 all (8) + t1.A halves (4),
// vmcnt(4) -> entering invariant = [t+1.A0,A1] in flight. Tail: p2 false -> no
// ph3 stage, vmcnt(0) once; last tile skips the wait.
__global__ __launch_bounds__(512) void gemm256(const u16* __restrict__ A,
                                               const u16* __restrict__ Bt,
                                               u16* __restrict__ C,
                                               int N, int K, int lda) {
    __shared__ __align__(16) u16 lds[65536];   // 128 KB
    const int t = threadIdx.x;
    const int ntn = N >> 8;
    const int nwg = gridDim.x;
    int bid = (int)blockIdx.x;
    bid = (bid & 7) * (nwg >> 3) + (bid >> 3);        // bijective XCD swizzle (nwg%8==0)
    const int tm = bid / ntn, tn = bid - tm * ntn;
    const size_t m0 = (size_t)tm << 8, n0 = (size_t)tn << 8;
    const int w = t >> 6, lane = t & 63;
    const int wr = w >> 2, wc = w & 3;                // 2 (M) x 4 (N)

    // staging sources (16B per lane; inverse swizzle on global source)
    const int r0 = t >> 3;
    const int ksrc = (t & 7) ^ (r0 & 7);
    const u16* sA0 = A + (m0 + r0) * (size_t)lda + ksrc * 8;   // A rows 0..127
    const u16* sA1 = sA0 + (size_t)128 * lda;                  // A rows 128..255
    const u16* sB0 = Bt + (n0 + r0) * (size_t)K + ksrc * 8;    // B rows 0..127
    const u16* sB1 = sB0 + (size_t)128 * K;                    // B rows 128..255
    const size_t stA = (size_t)64 * lda, stB = (size_t)64 * K;

#define STAGE(bb, hh, src, str, ko)                                           \
    do {                                                                      \
        u16* d_ = lds + (bb) * 32768 + (hh) * 8192 + (w << 9);                \
        lds16((src) + (ko), d_);                                              \
        lds16((src) + (ko) + (str), d_ + 4096);                               \
    } while (0)

    // fragment read offsets
    const int kx = lane & 7;
    const int ks0 = (((lane >> 4) ^ kx) << 3);        // kc=0
    const int ks1 = (((4 + (lane >> 4)) ^ kx) << 3);  // kc=1
    const int arow = (wr << 7) + (lane & 15);         // + mq*64 + i*16
    const int brow = (wc << 6) + (lane & 15);         // + nq*32 + j*16

    f32x4 acc[8][4];
#pragma unroll
    for (int i = 0; i < 8; i++)
#pragma unroll
        for (int j = 0; j < 4; j++)
#pragma unroll
            for (int r = 0; r < 4; r++) acc[i][j][r] = 0.0f;

    const int NT = K >> 6;
    // prologue: tile0 (all 4 halves) + tile1 A halves; vmcnt(4)
    STAGE(0, 0, sA0, stA, 0); STAGE(0, 1, sA1, stA, 0);
    STAGE(0, 2, sB0, stB, 0); STAGE(0, 3, sB1, stB, 0);
    if (NT > 1) {
        STAGE(1, 0, sA0, stA, 64); STAGE(1, 1, sA1, stA, 64);
        asm volatile("s_waitcnt vmcnt(4)" ::: "memory");
    } else {
        asm volatile("s_waitcnt vmcnt(0)" ::: "memory");
    }
    __builtin_amdgcn_s_barrier();
    asm volatile("" ::: "memory");

    for (int kt = 0; kt < NT; kt++) {
        const int b = kt & 1;
        const u16* Lb = lds + b * 32768;
        const size_t ko1 = (size_t)(kt + 1) << 6;
        const size_t ko2 = (size_t)(kt + 2) << 6;
        const bool p1 = (kt + 1 < NT), p2 = (kt + 2 < NT);
        bf16x8 af[4][2], b0[2][2], b1[2][2];

        // ---------------- ph0: af(mq0) + B0 ----------------
#pragma unroll
        for (int i = 0; i < 4; i++) {
            const int ar = (arow + i * 16) << 6;
            af[i][0] = *reinterpret_cast<const bf16x8*>(Lb + ar + ks0);
            af[i][1] = *reinterpret_cast<const bf16x8*>(Lb + ar + ks1);
        }
#pragma unroll
        for (int j = 0; j < 2; j++) {
            const int br = 16384 + ((brow + j * 16) << 6);
            b0[j][0] = *reinterpret_cast<const bf16x8*>(Lb + br + ks0);
            b0[j][1] = *reinterpret_cast<const bf16x8*>(Lb + br + ks1);
        }
        if (p1) STAGE(b ^ 1, 2, sB0, stB, ko1);
        asm volatile("s_waitcnt lgkmcnt(8)" ::: "memory");   // pacing (12 reads issued)
        __builtin_amdgcn_s_barrier();
        asm volatile("s_waitcnt lgkmcnt(0)" ::: "memory");
        __builtin_amdgcn_sched_barrier(0);
        __builtin_amdgcn_s_setprio(1);
#pragma unroll
        for (int kc = 0; kc < 2; kc++)
#pragma unroll
            for (int i = 0; i < 4; i++)
#pragma unroll
                for (int j = 0; j < 2; j++)
                    acc[i][j] = __builtin_amdgcn_mfma_f32_16x16x32_bf16(
                        af[i][kc], b0[j][kc], acc[i][j], 0, 0, 0);
        __builtin_amdgcn_s_setprio(0);
        asm volatile("" ::: "memory");
        __builtin_amdgcn_s_barrier();

        // ---------------- ph1: B1 ----------------
#pragma unroll
        for (int j = 0; j < 2; j++) {
            const int br = 16384 + ((brow + 32 + j * 16) << 6);
            b1[j][0] = *reinterpret_cast<const bf16x8*>(Lb + br + ks0);
            b1[j][1] = *reinterpret_cast<const bf16x8*>(Lb + br + ks1);
        }
        if (p1) STAGE(b ^ 1, 3, sB1, stB, ko1);
        __builtin_amdgcn_s_barrier();
        asm volatile("s_waitcnt lgkmcnt(0)" ::: "memory");
        __builtin_amdgcn_sched_barrier(0);
        __builtin_amdgcn_s_setprio(1);
#pragma unroll
        for (int kc = 0; kc < 2; kc++)
#pragma unroll
            for (int i = 0; i < 4; i++)
#pragma unroll
                for (int j = 0; j < 2; j++)
                    acc[i][2 + j] = __builtin_amdgcn_mfma_f32_16x16x32_bf16(
                        af[i][kc], b1[j][kc], acc[i][2 + j], 0, 0, 0);
        __builtin_amdgcn_s_setprio(0);
        asm volatile("" ::: "memory");
        __builtin_amdgcn_s_barrier();

        // ---------------- ph2: af(mq1) ----------------
#pragma unroll
        for (int i = 0; i < 4; i++) {
            const int ar = (arow + 64 + i * 16) << 6;
            af[i][0] = *reinterpret_cast<const bf16x8*>(Lb + ar + ks0);
            af[i][1] = *reinterpret_cast<const bf16x8*>(Lb + ar + ks1);
        }
        __builtin_amdgcn_s_barrier();
        asm volatile("s_waitcnt lgkmcnt(0)" ::: "memory");
        __builtin_amdgcn_sched_barrier(0);
        __builtin_amdgcn_s_setprio(1);
#pragma unroll
        for (int kc = 0; kc < 2; kc++)
#pragma unroll
            for (int i = 0; i < 4; i++)
#pragma unroll
                for (int j = 0; j < 2; j++)
                    acc[4 + i][j] = __builtin_amdgcn_mfma_f32_16x16x32_bf16(
                        af[i][kc], b0[j][kc], acc[4 + i][j], 0, 0, 0);
        __builtin_amdgcn_s_setprio(0);
        asm volatile("" ::: "memory");
        __builtin_amdgcn_s_barrier();

        // ---------------- ph3: stage t+2.A (buf b), counted vmcnt ----------------
        if (p2) {
            STAGE(b, 0, sA0, stA, ko2);
            STAGE(b, 1, sA1, stA, ko2);
            asm volatile("s_waitcnt vmcnt(4)" ::: "memory");
        } else if (p1) {
            asm volatile("s_waitcnt vmcnt(0)" ::: "memory");
        }
        __builtin_amdgcn_s_barrier();                 // tile t+1 fully resident
        __builtin_amdgcn_s_setprio(1);
#pragma unroll
        for (int kc = 0; kc < 2; kc++)
#pragma unroll
            for (int i = 0; i < 4; i++)
#pragma unroll
                for (int j = 0; j < 2; j++)
                    acc[4 + i][2 + j] = __builtin_amdgcn_mfma_f32_16x16x32_bf16(
                        af[i][kc], b1[j][kc], acc[4 + i][2 + j], 0, 0, 0);
        __builtin_amdgcn_s_setprio(0);
        asm volatile("" ::: "memory");
        __builtin_amdgcn_s_barrier();
    }
#undef STAGE

    // epilogue: bf16 store
    const int crow = (lane >> 4) << 2, ccol = lane & 15;
#pragma unroll
    for (int i = 0; i < 8; i++)
#pragma unroll
        for (int j = 0; j < 4; j++) {
            size_t row = m0 + (wr << 7) + (i << 4) + crow;
            size_t col = n0 + (wc << 6) + (j << 4) + ccol;
#pragma unroll
            for (int r = 0; r < 4; r++)
                C[(row + r) * (size_t)N + col] = f2bf(acc[i][j][r]);
        }
}

// ============ 128x256 bf16 GEMM (BK=64, dbuf, counted vmcnt) — small/odd grids ============
// EPI: 2 = bf16 out, 3 = bf16 bias+relu out.
// bstride: if nonzero, Bt is batched per 2048 A-rows (Bt_eff = Bt + (m0>>11)*bstride).
template <int EPI>
__global__ __launch_bounds__(512) void gemm8p(const u16* __restrict__ A,
                                              const u16* __restrict__ Bt,
                                              void* __restrict__ Cv,
                                              const float* __restrict__ bias,
                                              int N, int K, int lda, size_t bstride) {
    __shared__ __align__(16) u16 lds[49152];   // 96 KB = 2 x 24576 u16
    const int t = threadIdx.x;
    const int ntn = N >> 8;
    const int nwg = gridDim.x;                 // must be % 8 == 0
    int bid = (int)blockIdx.x;
    bid = (bid & 7) * (nwg >> 3) + (bid >> 3);
    const int tm = bid / ntn, tn = bid - tm * ntn;
    const size_t m0 = (size_t)tm << 7, n0 = (size_t)tn << 8;
    const int w = t >> 6, lane = t & 63;
    const int wr = w >> 2, wc = w & 3;         // 2 (M) x 4 (N) waves
    const u16* Bt_e = Bt + (bstride ? (m0 >> 11) * bstride : 0);

    const int r0 = t >> 3;
    const int ksrc = (t & 7) ^ (r0 & 7);
    const u16* sA0 = A + (m0 + r0) * (size_t)lda + ksrc * 8;
    const u16* sA1 = sA0 + (size_t)64 * lda;
    const u16* sB0 = Bt_e + (n0 + r0) * (size_t)K + ksrc * 8;
    const u16* sB1 = sB0 + (size_t)64 * K;
    const u16* sB2 = sB0 + (size_t)128 * K;
    const u16* sB3 = sB0 + (size_t)192 * K;
    u16* dstW = lds + (w << 9);

    const int ao = ((wr << 6) | (lane & 15)) << 6;
    const int bo = 8192 + ((((wc << 6) | (lane & 15))) << 6);
    const int kx = lane & 7;
    const int ks0 = (((lane >> 4) ^ kx) << 3);
    const int ks1 = (((4 + (lane >> 4)) ^ kx) << 3);

    f32x4 acc[4][4];
#pragma unroll
    for (int i = 0; i < 4; i++)
#pragma unroll
        for (int j = 0; j < 4; j++)
#pragma unroll
            for (int r = 0; r < 4; r++) acc[i][j][r] = 0.0f;

    const int NT = K >> 6;
    lds16(sA0, dstW);          lds16(sA1, dstW + 4096);
    lds16(sB0, dstW + 8192);   lds16(sB1, dstW + 12288);
    lds16(sB2, dstW + 16384);  lds16(sB3, dstW + 20480);

    for (int kt = 0; kt < NT; kt++) {
        const int b = kt & 1;
        asm volatile("" ::: "memory");
        if (kt + 1 < NT) {
            const size_t ko = (size_t)(kt + 1) << 6;
            u16* d = dstW + (b ^ 1) * 24576;
            lds16(sA0 + ko, d);          lds16(sA1 + ko, d + 4096);
            lds16(sB0 + ko, d + 8192);   lds16(sB1 + ko, d + 12288);
            lds16(sB2 + ko, d + 16384);  lds16(sB3 + ko, d + 20480);
            asm volatile("s_waitcnt vmcnt(6)" ::: "memory");
        } else {
            asm volatile("s_waitcnt vmcnt(0)" ::: "memory");
        }
        __builtin_amdgcn_s_barrier();
        asm volatile("" ::: "memory");
        const u16* Lb = lds + b * 24576;
#pragma unroll
        for (int kc = 0; kc < 2; kc++) {
            const int ksl = kc ? ks1 : ks0;
            bf16x8 af[4], bfr[4];
#pragma unroll
            for (int i = 0; i < 4; i++)
                af[i] = *reinterpret_cast<const bf16x8*>(Lb + ao + i * 1024 + ksl);
#pragma unroll
            for (int j = 0; j < 4; j++)
                bfr[j] = *reinterpret_cast<const bf16x8*>(Lb + bo + j * 1024 + ksl);
            __builtin_amdgcn_s_setprio(1);
#pragma unroll
            for (int i = 0; i < 4; i++)
#pragma unroll
                for (int j = 0; j < 4; j++)
                    acc[i][j] = __builtin_amdgcn_mfma_f32_16x16x32_bf16(af[i], bfr[j], acc[i][j], 0, 0, 0);
            __builtin_amdgcn_s_setprio(0);
        }
        asm volatile("" ::: "memory");
        __builtin_amdgcn_s_barrier();
    }

    const int crow = (lane >> 4) << 2, ccol = lane & 15;
#pragma unroll
    for (int i = 0; i < 4; i++)
#pragma unroll
        for (int j = 0; j < 4; j++) {
            size_t row = m0 + (wr << 6) + (i << 4) + crow;
            size_t col = n0 + (wc << 6) + (j << 4) + ccol;
#pragma unroll
            for (int r = 0; r < 4; r++) {
                float v = acc[i][j][r];
                if (EPI == 3) { v += bias[col]; v = fmaxf(v, 0.0f); }
                ((u16*)Cv)[(row + r) * (size_t)N + col] = f2bf(v);
            }
        }
}

// ===== KtV partials: per (bh, split of 128 rows), 64x64 fp32 outer-product accumulate =====
// kv layout: [8192][2048] bf16, cols 0..1023 = K, 1024..2047 = V.
__global__ __launch_bounds__(256) void ktv_kernel(const u16* __restrict__ kv,
                                                  float* __restrict__ part) {
    const int bh = blockIdx.x, split = blockIdx.y;
    const int b = bh >> 4, h = bh & 15;
    const u16* Kp = kv + (size_t)b * 2048 * 2048 + h * 64;
    const u16* Vp = Kp + 1024;
    __shared__ float ks[8][64], vs[8][64];
    float acc[16];
#pragma unroll
    for (int i = 0; i < 16; i++) acc[i] = 0.0f;
    const int t = threadIdx.x, r = t >> 4, c = t & 15;
    const int lr = t >> 5, lc = (t & 31) * 2;
    for (int l0 = split * 128; l0 < split * 128 + 128; l0 += 8) {
        unsigned kk = *(const unsigned*)(Kp + (size_t)(l0 + lr) * 2048 + lc);
        unsigned vv = *(const unsigned*)(Vp + (size_t)(l0 + lr) * 2048 + lc);
        ks[lr][lc] = bf2f((u16)kk); ks[lr][lc + 1] = bf2f((u16)(kk >> 16));
        vs[lr][lc] = bf2f((u16)vv); vs[lr][lc + 1] = bf2f((u16)(vv >> 16));
        __syncthreads();
#pragma unroll
        for (int i = 0; i < 8; i++) {
            float kvr[4], vw[4];
#pragma unroll
            for (int a = 0; a < 4; a++) { kvr[a] = ks[i][r + 16 * a]; vw[a] = vs[i][c + 16 * a]; }
#pragma unroll
            for (int a = 0; a < 4; a++)
#pragma unroll
                for (int q = 0; q < 4; q++) acc[a * 4 + q] += kvr[a] * vw[q];
        }
        __syncthreads();
    }
    float* o = part + ((size_t)split * 64 + bh) * 4096;
#pragma unroll
    for (int a = 0; a < 4; a++)
#pragma unroll
        for (int q = 0; q < 4; q++) o[(r + 16 * a) * 64 + (c + 16 * q)] = acc[a * 4 + q];
}

__global__ __launch_bounds__(256) void ktv_reduce(const float* __restrict__ part,
                                                  float* __restrict__ ktv) {
    int i = blockIdx.x * 256 + threadIdx.x;  // 64*4096 = 262144
    float s = 0.0f;
#pragma unroll
    for (int sp = 0; sp < 16; sp++) s += part[(size_t)sp * 262144 + i];
    ktv[i] = s;
}

// ===== W'^T_b[n][h*64+i] = sum_j (KtV_bh[i][j]/8) * Wo[h*64+j][n]  -> bf16 =====
__global__ __launch_bounds__(256) void wprime_kernel(const float* __restrict__ ktv,
                                                     const float* __restrict__ Wo,
                                                     u16* __restrict__ wp) {
    const int n = blockIdx.x * 256 + threadIdx.x;   // blockIdx.x in [0,4)
    const int h = blockIdx.y, b = blockIdx.z;
    const float* kt = ktv + ((size_t)(b * 16 + h) << 12);
    float acc[64];
#pragma unroll
    for (int i = 0; i < 64; i++) acc[i] = 0.0f;
    for (int j = 0; j < 64; j++) {
        float w = Wo[(size_t)(h * 64 + j) * 1024 + n];
#pragma unroll
        for (int i = 0; i < 64; i++) acc[i] += kt[i * 64 + j] * w;
    }
    u16* o = wp + ((size_t)b << 20) + (size_t)n * 1024 + h * 64;
    u16 ob[64];
#pragma unroll
    for (int i = 0; i < 64; i++) ob[i] = f2bf(acc[i] * 0.125f);
#pragma unroll
    for (int i = 0; i < 8; i++)
        ((uint4*)o)[i] = ((const uint4*)ob)[i];
}

// ===== LN1: h1b = bf16(LN(x_bf + attn_bf)) =====
__global__ __launch_bounds__(256) void ln1_kernel(const u16* __restrict__ xb,
                                                  const u16* __restrict__ attn,
                                                  const float* __restrict__ g,
                                                  const float* __restrict__ be,
                                                  u16* __restrict__ outB) {
    __shared__ float sm[4];
    const int row = blockIdx.x, t = threadIdx.x;
    const ushort4 xv = ((const ushort4*)(xb + (size_t)row * 1024))[t];
    const ushort4 av = ((const ushort4*)(attn + (size_t)row * 1024))[t];
    float x0 = bf2f(xv.x) + bf2f(av.x), x1 = bf2f(xv.y) + bf2f(av.y);
    float x2 = bf2f(xv.z) + bf2f(av.z), x3 = bf2f(xv.w) + bf2f(av.w);
    float s = x0 + x1 + x2 + x3;
#pragma unroll
    for (int off = 32; off > 0; off >>= 1) s += __shfl_down(s, off);
    if ((t & 63) == 0) sm[t >> 6] = s;
    __syncthreads();
    const float mean = (sm[0] + sm[1] + sm[2] + sm[3]) * (1.0f / 1024.0f);
    __syncthreads();
    x0 -= mean; x1 -= mean; x2 -= mean; x3 -= mean;
    float s2 = x0 * x0 + x1 * x1 + x2 * x2 + x3 * x3;
#pragma unroll
    for (int off = 32; off > 0; off >>= 1) s2 += __shfl_down(s2, off);
    if ((t & 63) == 0) sm[t >> 6] = s2;
    __syncthreads();
    const float var = (sm[0] + sm[1] + sm[2] + sm[3]) * (1.0f / 1024.0f);
    const float rs = rsqrtf(var + 1e-5f);
    const float4 gv = ((const float4*)g)[t];
    const float4 bv = ((const float4*)be)[t];
    ushort4 ob;
    ob.x = f2bf(x0 * rs * gv.x + bv.x);
    ob.y = f2bf(x1 * rs * gv.y + bv.y);
    ob.z = f2bf(x2 * rs * gv.z + bv.z);
    ob.w = f2bf(x3 * rs * gv.w + bv.w);
    ((ushort4*)(outB + (size_t)row * 1024))[t] = ob;
}

// ===== LN2: out = f32(LN(ff_bf + h1_bf)) =====
__global__ __launch_bounds__(256) void ln2_kernel(const u16* __restrict__ ff,
                                                  const u16* __restrict__ h1,
                                                  const float* __restrict__ g,
                                                  const float* __restrict__ be,
                                                  float* __restrict__ outF) {
    __shared__ float sm[4];
    const int row = blockIdx.x, t = threadIdx.x;
    const ushort4 fv = ((const ushort4*)(ff + (size_t)row * 1024))[t];
    const ushort4 hv = ((const ushort4*)(h1 + (size_t)row * 1024))[t];
    float x0 = bf2f(fv.x) + bf2f(hv.x), x1 = bf2f(fv.y) + bf2f(hv.y);
    float x2 = bf2f(fv.z) + bf2f(hv.z), x3 = bf2f(fv.w) + bf2f(hv.w);
    float s = x0 + x1 + x2 + x3;
#pragma unroll
    for (int off = 32; off > 0; off >>= 1) s += __shfl_down(s, off);
    if ((t & 63) == 0) sm[t >> 6] = s;
    __syncthreads();
    const float mean = (sm[0] + sm[1] + sm[2] + sm[3]) * (1.0f / 1024.0f);
    __syncthreads();
    x0 -= mean; x1 -= mean; x2 -= mean; x3 -= mean;
    float s2 = x0 * x0 + x1 * x1 + x2 * x2 + x3 * x3;
#pragma unroll
    for (int off = 32; off > 0; off >>= 1) s2 += __shfl_down(s2, off);
    if ((t & 63) == 0) sm[t >> 6] = s2;
    __syncthreads();
    const float var = (sm[0] + sm[1] + sm[2] + sm[3]) * (1.0f / 1024.0f);
    const float rs = rsqrtf(var + 1e-5f);
    const float4 gv = ((const float4*)g)[t];
    const float4 bv = ((const float4*)be)[t];
    float4 o;
    o.x = x0 * rs * gv.x + bv.x;
    o.y = x1 * rs * gv.y + bv.y;
    o.z = x2 * rs * gv.z + bv.z;
    o.w = x3 * rs * gv.w + bv.w;
    ((float4*)(outF + (size_t)row * 1024))[t] = o;
}

extern "C" void kernel_launch(void* const* d_in, const int* in_sizes, int n_in,
                              void* d_out, int out_size, void* d_ws, size_t ws_size,
                              hipStream_t stream) {
    const float* seq = (const float*)d_in[0];
    const float* Wq  = (const float*)d_in[1];
    const float* Wk  = (const float*)d_in[2];
    const float* Wv  = (const float*)d_in[3];
    const float* Wo  = (const float*)d_in[4];
    const float* g1  = (const float*)d_in[5];
    const float* b1  = (const float*)d_in[6];
    const float* Wl  = (const float*)d_in[7];
    const float* bl  = (const float*)d_in[8];
    const float* g2  = (const float*)d_in[9];
    const float* b2  = (const float*)d_in[10];

    char* ws = (char*)d_ws;
    const size_t MB = 1024 * 1024;
    u16*   x_bf  = (u16*)(ws + 0);              // 16 MB [8192][1024]
    u16*   wt    = (u16*)(ws + 16 * MB);        // 8 MB: [Wq, Wk^T, Wv^T, Wl] bf16
    u16*   kv    = (u16*)(ws + 24 * MB);        // 32 MB [8192][2048] (dead after ktv)
    float* kpart = (float*)(ws + 56 * MB);      // 16 MB [16][64][4096] (dead after reduce)
    u16*   attn  = (u16*)(ws + 56 * MB);        // 16 MB (reuses kpart)
    float* ktv   = (float*)(ws + 72 * MB);      // 1 MB  [64][64][64]
    u16*   wpr   = (u16*)(ws + 73 * MB);        // 8 MB  [4][1024][1024] W'^T per batch
    u16*   wcomb = (u16*)(ws + 81 * MB);        // 8 MB  [4][1024][1024] Wcomb^T per batch
    u16*   h1b   = (u16*)(ws + 89 * MB);        // 16 MB
    u16*   ffb   = (u16*)(ws + 105 * MB);       // 16 MB

    // 1. x_bf = bf16(seq + positional)
    prep_x<<<dim3(8192), dim3(256), 0, stream>>>(seq, x_bf);
    // 2. weights -> bf16
    prep_w<<<dim3(32, 32, 4), dim3(32, 8), 0, stream>>>(Wq, Wk, Wv, Wl, wt);
    // 3. kv = x @ [Wk|Wv]: [8192,1024]@[1024,2048] -> bf16  (8-phase 256^2; grid 32x8=256)
    gemm256<<<dim3(256), dim3(512), 0, stream>>>(x_bf, wt + (size_t)1 * MB, kv,
                                                 2048, 1024, 1024);
    // 4. KtV per (b,h), deterministic two-stage
    ktv_kernel<<<dim3(64, 16), dim3(256), 0, stream>>>(kv, kpart);
    ktv_reduce<<<dim3(1024), dim3(256), 0, stream>>>(kpart, ktv);
    // 5. W'^T_b = (blockdiag(KtV_b)/8 @ W_o)^T -> bf16
    wprime_kernel<<<dim3(4, 16, 4), dim3(256), 0, stream>>>(ktv, Wo, wpr);
    // 6. Wcomb^T_b = W'^T_b @ Wq: grid 32x4 = 128
    gemm8p<2><<<dim3(128), dim3(512), 0, stream>>>(wpr, wt, wcomb, nullptr,
                                                   1024, 1024, 1024, 0);
    // 7. attn = x @ Wcomb_b -> bf16  (B batched per 2048 rows; grid 64x4 = 256)
    gemm8p<2><<<dim3(256), dim3(512), 0, stream>>>(x_bf, wcomb, attn, nullptr,
                                                   1024, 1024, 1024, (size_t)1024 * 1024);
    // 8. h1b = bf16(LN(x_bf + attn))
    ln1_kernel<<<dim3(8192), dim3(256), 0, stream>>>(x_bf, attn, g1, b1, h1b);
    // 9. ff = relu(h1 @ Wl^T + bl) -> bf16  (grid 256)
    gemm8p<3><<<dim3(256), dim3(512), 0, stream>>>(h1b, wt + (size_t)3 * MB, ffb,
                                                   bl, 1024, 1024, 1024, 0);
    // 10. out = LN(ff + h1)
    ln2_kernel<<<dim3(8192), dim3(256), 0, stream>>>(ffb, h1b, g2, b2, (float*)d_out);
}